// Round 1
// baseline (403.916 us; speedup 1.0000x reference)
//
#include <hip/hip_runtime.h>
#include <cstdint>

typedef unsigned short UST;
typedef __bf16 v8bf __attribute__((ext_vector_type(8)));
typedef float v4f __attribute__((ext_vector_type(4)));

__device__ __forceinline__ UST f2b(float f) {
  union { float f; uint32_t u; } c; c.f = f;
  uint32_t u = c.u;
  u += 0x7fffu + ((u >> 16) & 1u);   // RNE
  return (UST)(u >> 16);
}
__device__ __forceinline__ float b2f(UST h) {
  union { uint32_t u; float f; } c; c.u = ((uint32_t)h) << 16;
  return c.f;
}

// ---------------- cast x f32 -> bf16, 8 elems/thread ----------------
__global__ __launch_bounds__(256) void k_cast(const float* __restrict__ src,
                                              UST* __restrict__ dst) {
  size_t i = (size_t)blockIdx.x * 256 + threadIdx.x;
  const float4* s4 = reinterpret_cast<const float4*>(src) + 2 * i;
  float4 a = s4[0], b = s4[1];
  union { UST s[8]; uint4 v; } r;
  r.s[0] = f2b(a.x); r.s[1] = f2b(a.y); r.s[2] = f2b(a.z); r.s[3] = f2b(a.w);
  r.s[4] = f2b(b.x); r.s[5] = f2b(b.y); r.s[6] = f2b(b.z); r.s[7] = f2b(b.w);
  reinterpret_cast<uint4*>(dst)[i] = r.v;
}

// ------------- transpose+cast: W [K][N] f32 -> dst [N][K] bf16 -------------
__global__ __launch_bounds__(256) void k_castT(const float* __restrict__ W,
                                               UST* __restrict__ dst, int N, int K) {
  __shared__ float tile[32][33];
  int nt = blockIdx.x * 32, kt = blockIdx.y * 32;
  int tx = threadIdx.x, ty = threadIdx.y;  // 32 x 8
#pragma unroll
  for (int r = 0; r < 4; ++r)
    tile[ty + r * 8][tx] = W[(size_t)(kt + ty + r * 8) * N + nt + tx];
  __syncthreads();
#pragma unroll
  for (int r = 0; r < 4; ++r)
    dst[(size_t)(nt + ty + r * 8) * K + kt + tx] = f2b(tile[tx][ty + r * 8]);
}

// ---------------- bf16 GEMM: C[M][N] = A[M][K] * Bt[N][K]^T ----------------
// 128x128 tile, BK=32, 4 waves (2x2 of 64x64), mfma_f32_16x16x32_bf16.
// EPI=0: bf16 C.  EPI=1: f32 C + bias.
template <int EPI>
__global__ __launch_bounds__(256) void k_gemm(const UST* __restrict__ A,
                                              const UST* __restrict__ Bt,
                                              void* __restrict__ Cv,
                                              const float* __restrict__ bias,
                                              int M, int N, int K) {
  constexpr int PAD = 40;  // 80B rows: 16B-aligned, 2-way banks on frag reads
  __shared__ __align__(16) UST a_s[128 * PAD];
  __shared__ __align__(16) UST b_s[128 * PAD];
  int tid = threadIdx.x;
  int lane = tid & 63, w = tid >> 6;
  int lr = lane & 15, lg = lane >> 4;
  int wr = w >> 1, wc = w & 1;
  int mBlk = blockIdx.y * 128, nBlk = blockIdx.x * 128;

  v4f acc[4][4];
#pragma unroll
  for (int i = 0; i < 4; ++i)
#pragma unroll
    for (int j = 0; j < 4; ++j) acc[i][j] = (v4f){0.f, 0.f, 0.f, 0.f};

  int sr = tid >> 1, sc = (tid & 1) * 16;  // 128 rows x 32 cols, 16 elems/thread
  const UST* Ap = A + (size_t)(mBlk + sr) * K + sc;
  const UST* Bp = Bt + (size_t)(nBlk + sr) * K + sc;
  UST* asw = a_s + sr * PAD + sc;
  UST* bsw = b_s + sr * PAD + sc;

  for (int k0 = 0; k0 < K; k0 += 32) {
    __syncthreads();
    *(uint4*)asw = *(const uint4*)Ap;
    *(uint4*)(asw + 8) = *(const uint4*)(Ap + 8);
    *(uint4*)bsw = *(const uint4*)Bp;
    *(uint4*)(bsw + 8) = *(const uint4*)(Bp + 8);
    Ap += 32; Bp += 32;
    __syncthreads();
    v8bf af[4], bfv[4];
#pragma unroll
    for (int mt = 0; mt < 4; ++mt)
      af[mt] = *(const v8bf*)&a_s[(wr * 64 + mt * 16 + lr) * PAD + lg * 8];
#pragma unroll
    for (int nt = 0; nt < 4; ++nt)
      bfv[nt] = *(const v8bf*)&b_s[(wc * 64 + nt * 16 + lr) * PAD + lg * 8];
#pragma unroll
    for (int mt = 0; mt < 4; ++mt)
#pragma unroll
      for (int nt = 0; nt < 4; ++nt)
        acc[mt][nt] = __builtin_amdgcn_mfma_f32_16x16x32_bf16(af[mt], bfv[nt],
                                                              acc[mt][nt], 0, 0, 0);
  }

  // C/D layout (m89/m91-verified): col = lane&15, row = 4*(lane>>4)+reg
  int row0 = mBlk + wr * 64 + lg * 4;
  int col0 = nBlk + wc * 64 + lr;
#pragma unroll
  for (int mt = 0; mt < 4; ++mt)
#pragma unroll
    for (int nt = 0; nt < 4; ++nt)
#pragma unroll
      for (int r = 0; r < 4; ++r) {
        int row = row0 + mt * 16 + r;
        int col = col0 + nt * 16;
        if constexpr (EPI == 0) {
          ((UST*)Cv)[(size_t)row * N + col] = f2b(acc[mt][nt][r]);
        } else {
          ((float*)Cv)[(size_t)row * N + col] = acc[mt][nt][r] + bias[col];
        }
      }
}

// ---------------- RoPE on q,k (q pre-scaled by 1/sqrt(64)) ----------------
// qkv bf16 [4096][3072]; qh [B][32][L][64]; kh [B][8][L][64]
__global__ __launch_bounds__(256) void k_rope(const UST* __restrict__ qkv,
                                              const float* __restrict__ cosT,
                                              const float* __restrict__ sinT,
                                              UST* __restrict__ qh,
                                              UST* __restrict__ kh) {
  int idx = blockIdx.x * 256 + threadIdx.x;  // B*L*40*32 = 5242880 exact
  int d = idx & 31;
  int hh = (idx >> 5) % 40;
  int row = idx / 1280;  // b*2048 + l
  int l = row & 2047, b = row >> 11;
  int col = (hh < 32) ? hh * 64 : 2048 + (hh - 32) * 64;
  float t1 = b2f(qkv[(size_t)row * 3072 + col + d]);
  float t2 = b2f(qkv[(size_t)row * 3072 + col + d + 32]);
  float c = cosT[l * 64 + d], s = sinT[l * 64 + d];  // halves identical
  float o1 = t1 * c - t2 * s;
  float o2 = t2 * c + t1 * s;
  if (hh < 32) {
    size_t base = (((size_t)b * 32 + hh) * 2048 + l) * 64 + d;
    qh[base] = f2b(o1 * 0.125f);
    qh[base + 32] = f2b(o2 * 0.125f);
  } else {
    size_t base = (((size_t)b * 8 + (hh - 32)) * 2048 + l) * 64 + d;
    kh[base] = f2b(o1);
    kh[base + 32] = f2b(o2);
  }
}

// ---------------- V transpose: qkv v-slice -> vt [B][8][64][L] ----------------
__global__ __launch_bounds__(256) void k_vtrans(const UST* __restrict__ qkv,
                                                UST* __restrict__ vt) {
  __shared__ __align__(16) UST tl[64][72];
  int lt = blockIdx.x, bg = blockIdx.y;
  int b = bg >> 3, g = bg & 7;
  int t = threadIdx.x;
  int li = t >> 2, d0 = (t & 3) * 16;
  const UST* src = qkv + (size_t)(b * 2048 + lt * 64 + li) * 3072 + 2560 + g * 64 + d0;
  *(uint4*)&tl[li][d0] = *(const uint4*)src;
  *(uint4*)&tl[li][d0 + 8] = *(const uint4*)(src + 8);
  __syncthreads();
  int d = t >> 2, l0 = (t & 3) * 16;
  union { UST u[8]; uint4 v; } r0, r1;
#pragma unroll
  for (int e = 0; e < 8; ++e) r0.u[e] = tl[l0 + e][d];
#pragma unroll
  for (int e = 0; e < 8; ++e) r1.u[e] = tl[l0 + 8 + e][d];
  UST* dstp = vt + (size_t)((b * 8 + g) * 64 + d) * 2048 + (size_t)lt * 64 + l0;
  *(uint4*)dstp = r0.v;
  *(uint4*)(dstp + 8) = r1.v;
}

// ---------------- causal flash attention ----------------
// grid (L/64, H, B); 4 waves; wave w owns q rows qt*64+w*16..+15.
__global__ __launch_bounds__(256) void k_attn(const UST* __restrict__ qh,
                                              const UST* __restrict__ kh,
                                              const UST* __restrict__ vt,
                                              UST* __restrict__ outp) {
  constexpr int PAD = 72;  // 144B rows: 16B-aligned, 2-way banks
  __shared__ __align__(16) UST k_s[64 * PAD];
  __shared__ __align__(16) UST v_s[64 * PAD];
  __shared__ __align__(16) UST p_s[4][16 * PAD];
  int qt = blockIdx.x, h = blockIdx.y, b = blockIdx.z;
  int g = h >> 2;  // GROUP_SIZE = 4
  int tid = threadIdx.x, w = tid >> 6, lane = tid & 63;
  int lr = lane & 15, lg = lane >> 4;
  int qbase = qt * 64 + w * 16;

  // Q fragments (A-layout: row = lane&15, k = 8*(lane>>4)+e), Q pre-scaled
  const UST* qp = qh + ((size_t)(b * 32 + h) * 2048 + qbase + lr) * 64 + lg * 8;
  v8bf qf0 = *(const v8bf*)qp;
  v8bf qf1 = *(const v8bf*)(qp + 32);

  float m[4], lsum[4];
  v4f o[4];
#pragma unroll
  for (int r = 0; r < 4; ++r) { m[r] = -1e30f; lsum[r] = 0.f; }
#pragma unroll
  for (int d = 0; d < 4; ++d) o[d] = (v4f){0.f, 0.f, 0.f, 0.f};

  int sr = tid >> 2, sc = (tid & 3) * 16;
  const UST* kp0 = kh + ((size_t)(b * 8 + g) * 2048 + sr) * 64 + sc;
  const UST* vp0 = vt + ((size_t)(b * 8 + g) * 64 + sr) * 2048 + sc;

  for (int j = 0; j <= qt; ++j) {
    __syncthreads();
    {
      const UST* kp = kp0 + (size_t)j * 4096;  // 64 rows * 64
      *(uint4*)&k_s[sr * PAD + sc] = *(const uint4*)kp;
      *(uint4*)&k_s[sr * PAD + sc + 8] = *(const uint4*)(kp + 8);
      const UST* vp = vp0 + (size_t)j * 64;
      *(uint4*)&v_s[sr * PAD + sc] = *(const uint4*)vp;
      *(uint4*)&v_s[sr * PAD + sc + 8] = *(const uint4*)(vp + 8);
    }
    __syncthreads();

    // S = Q K^T  (B-frag of K^T == A-style read of K rows)
    v4f s[4];
#pragma unroll
    for (int ct = 0; ct < 4; ++ct) {
      v8bf kf0 = *(const v8bf*)&k_s[(ct * 16 + lr) * PAD + lg * 8];
      v8bf kf1 = *(const v8bf*)&k_s[(ct * 16 + lr) * PAD + 32 + lg * 8];
      v4f z = (v4f){0.f, 0.f, 0.f, 0.f};
      z = __builtin_amdgcn_mfma_f32_16x16x32_bf16(qf0, kf0, z, 0, 0, 0);
      z = __builtin_amdgcn_mfma_f32_16x16x32_bf16(qf1, kf1, z, 0, 0, 0);
      s[ct] = z;
    }
    if (j == qt) {  // diagonal tile: causal mask
#pragma unroll
      for (int ct = 0; ct < 4; ++ct)
#pragma unroll
        for (int r = 0; r < 4; ++r) {
          int qrow = qbase + lg * 4 + r;
          int kcol = j * 64 + ct * 16 + lr;
          s[ct][r] = (kcol > qrow) ? -1e30f : s[ct][r];
        }
    }
    // online softmax (rows live in 16-lane groups; reduce via shfl_xor 1..8)
    float alpha[4], rs[4];
#pragma unroll
    for (int r = 0; r < 4; ++r) {
      float v0 = fmaxf(fmaxf(s[0][r], s[1][r]), fmaxf(s[2][r], s[3][r]));
#pragma unroll
      for (int off = 1; off <= 8; off <<= 1) v0 = fmaxf(v0, __shfl_xor(v0, off));
      float mn = fmaxf(m[r], v0);
      alpha[r] = __expf(m[r] - mn);
      m[r] = mn;
      rs[r] = 0.f;
    }
#pragma unroll
    for (int ct = 0; ct < 4; ++ct)
#pragma unroll
      for (int r = 0; r < 4; ++r) {
        float p = __expf(s[ct][r] - m[r]);
        s[ct][r] = p;
        rs[r] += p;
      }
#pragma unroll
    for (int r = 0; r < 4; ++r) {
#pragma unroll
      for (int off = 1; off <= 8; off <<= 1) rs[r] += __shfl_xor(rs[r], off);
      lsum[r] = lsum[r] * alpha[r] + rs[r];
    }
#pragma unroll
    for (int d = 0; d < 4; ++d)
#pragma unroll
      for (int r = 0; r < 4; ++r) o[d][r] *= alpha[r];

    // P (D-layout) -> LDS -> A-layout fragments
#pragma unroll
    for (int ct = 0; ct < 4; ++ct)
#pragma unroll
      for (int r = 0; r < 4; ++r)
        p_s[w][(lg * 4 + r) * PAD + ct * 16 + lr] = f2b(s[ct][r]);
    __syncthreads();

#pragma unroll
    for (int kk = 0; kk < 2; ++kk) {
      v8bf pa = *(const v8bf*)&p_s[w][lr * PAD + kk * 32 + lg * 8];
#pragma unroll
      for (int dt = 0; dt < 4; ++dt) {
        v8bf vb = *(const v8bf*)&v_s[(dt * 16 + lr) * PAD + kk * 32 + lg * 8];
        o[dt] = __builtin_amdgcn_mfma_f32_16x16x32_bf16(pa, vb, o[dt], 0, 0, 0);
      }
    }
  }

  float inv[4];
#pragma unroll
  for (int r = 0; r < 4; ++r) inv[r] = 1.f / lsum[r];
  // write O as [B*L][H*64] bf16 (input matrix of the output GEMM)
  size_t rowb = ((size_t)b * 2048 + qbase + lg * 4) * 2048 + h * 64 + lr;
#pragma unroll
  for (int dt = 0; dt < 4; ++dt)
#pragma unroll
    for (int r = 0; r < 4; ++r)
      outp[rowb + (size_t)r * 2048 + dt * 16] = f2b(o[dt][r] * inv[r]);
}

// ---------------- launch ----------------
extern "C" void kernel_launch(void* const* d_in, const int* in_sizes, int n_in,
                              void* d_out, int out_size, void* d_ws, size_t ws_size,
                              hipStream_t stream) {
  const float* x    = (const float*)d_in[0];
  // d_in[1] = mask (causal, known analytically) — ignored
  const float* cosT = (const float*)d_in[2];
  const float* sinT = (const float*)d_in[3];
  const float* Wq   = (const float*)d_in[4];
  const float* Wk   = (const float*)d_in[5];
  const float* Wv   = (const float*)d_in[6];
  const float* Wo   = (const float*)d_in[7];
  const float* bo   = (const float*)d_in[8];
  float* out = (float*)d_out;

  char* ws = (char*)d_ws;
  // workspace layout (bytes)
  UST* xb   = (UST*)(ws);                       // 4096*2048*2  = 16777216
  UST* wcat = (UST*)(ws + 16777216);            // 3072*2048*2  = 12582912
  UST* wot  = (UST*)(ws + 29360128);            // 2048*2048*2  =  8388608
  UST* qkv  = (UST*)(ws + 37748736);            // 4096*3072*2  = 25165824
  UST* qhp  = (UST*)(ws + 62914560);            // 16777216
  UST* khp  = (UST*)(ws + 79691776);            //  4194304
  UST* vtp  = (UST*)(ws + 83886080);            //  4194304  (end 88080384)
  UST* attn_o = xb;  // xb dead after QKV GEMM; reuse for attention output

  k_cast<<<4096, 256, 0, stream>>>(x, xb);
  k_castT<<<dim3(64, 64), dim3(32, 8), 0, stream>>>(Wq, wcat, 2048, 2048);
  k_castT<<<dim3(16, 64), dim3(32, 8), 0, stream>>>(Wk, wcat + (size_t)2048 * 2048, 512, 2048);
  k_castT<<<dim3(16, 64), dim3(32, 8), 0, stream>>>(Wv, wcat + (size_t)2560 * 2048, 512, 2048);
  k_castT<<<dim3(64, 64), dim3(32, 8), 0, stream>>>(Wo, wot, 2048, 2048);

  k_gemm<0><<<dim3(24, 32), 256, 0, stream>>>(xb, wcat, qkv, nullptr, 4096, 3072, 2048);
  k_rope<<<20480, 256, 0, stream>>>(qkv, cosT, sinT, qhp, khp);
  k_vtrans<<<dim3(32, 16), 256, 0, stream>>>(qkv, vtp);
  k_attn<<<dim3(32, 32, 2), 256, 0, stream>>>(qhp, khp, vtp, attn_o);
  k_gemm<1><<<dim3(16, 32), 256, 0, stream>>>(attn_o, wot, out, bo, 4096, 2048, 2048);
}

// Round 2
// 326.083 us; speedup vs baseline: 1.2387x; 1.2387x over previous
//
#include <hip/hip_runtime.h>
#include <cstdint>

typedef unsigned short UST;
typedef __bf16 v8bf __attribute__((ext_vector_type(8)));
typedef float v4f __attribute__((ext_vector_type(4)));

static __device__ __forceinline__ UST f2b(float f) {
  union { float f; uint32_t u; } c; c.f = f;
  uint32_t u = c.u;
  u += 0x7fffu + ((u >> 16) & 1u);   // RNE
  return (UST)(u >> 16);
}
static __device__ __forceinline__ float b2f(UST h) {
  union { uint32_t u; float f; } c; c.u = ((uint32_t)h) << 16;
  return c.f;
}

// async global->LDS, 16B per lane; lds ptr must be wave-uniform base (lane*16 auto)
static __device__ __forceinline__ void gl_lds16(const UST* g, UST* l) {
  __builtin_amdgcn_global_load_lds(
      (const __attribute__((address_space(1))) void*)g,
      (__attribute__((address_space(3))) void*)l, 16, 0, 0);
}

// ---------------- cast x f32 -> bf16, 8 elems/thread ----------------
__global__ __launch_bounds__(256) void k_cast(const float* __restrict__ src,
                                              UST* __restrict__ dst) {
  size_t i = (size_t)blockIdx.x * 256 + threadIdx.x;
  const float4* s4 = reinterpret_cast<const float4*>(src) + 2 * i;
  float4 a = s4[0], b = s4[1];
  union { UST s[8]; uint4 v; } r;
  r.s[0] = f2b(a.x); r.s[1] = f2b(a.y); r.s[2] = f2b(a.z); r.s[3] = f2b(a.w);
  r.s[4] = f2b(b.x); r.s[5] = f2b(b.y); r.s[6] = f2b(b.z); r.s[7] = f2b(b.w);
  reinterpret_cast<uint4*>(dst)[i] = r.v;
}

// ------------- transpose+cast: W [K][N] f32 -> dst [N][K] bf16 -------------
__global__ __launch_bounds__(256) void k_castT(const float* __restrict__ W,
                                               UST* __restrict__ dst, int N, int K) {
  __shared__ float tile[32][33];
  int nt = blockIdx.x * 32, kt = blockIdx.y * 32;
  int tx = threadIdx.x, ty = threadIdx.y;  // 32 x 8
#pragma unroll
  for (int r = 0; r < 4; ++r)
    tile[ty + r * 8][tx] = W[(size_t)(kt + ty + r * 8) * N + nt + tx];
  __syncthreads();
#pragma unroll
  for (int r = 0; r < 4; ++r)
    dst[(size_t)(nt + ty + r * 8) * K + kt + tx] = f2b(tile[tx][ty + r * 8]);
}

// ---------------- bf16 GEMM (m97 structure): C = A * Bt^T ----------------
// 128x128 tile, BK=32, 4 waves (2x2 of 64x64), linear LDS + global_load_lds x16.
// EPI=0: bf16 C.  EPI=1: f32 C + bias.
template <int EPI>
__global__ __launch_bounds__(256) void k_gemm(const UST* __restrict__ A,
                                              const UST* __restrict__ Bt,
                                              void* __restrict__ Cv,
                                              const float* __restrict__ bias,
                                              int M, int N, int K) {
  __shared__ __align__(16) UST a_s[128 * 32];
  __shared__ __align__(16) UST b_s[128 * 32];
  int tid = threadIdx.x;
  int lane = tid & 63, w = tid >> 6;
  int lr = lane & 15, lg = lane >> 4;
  int wr = w >> 1, wc = w & 1;
  int mBlk = blockIdx.y * 128, nBlk = blockIdx.x * 128;

  v4f acc[4][4];
#pragma unroll
  for (int i = 0; i < 4; ++i)
#pragma unroll
    for (int j = 0; j < 4; ++j) acc[i][j] = (v4f){0.f, 0.f, 0.f, 0.f};

  // staging: thread t covers tile bytes t*16 -> row t/4, elems (t&3)*8
  int stR = tid >> 2, stC = (tid & 3) * 8;
  const UST* Ag = A + (size_t)(mBlk + stR) * K + stC;
  const UST* Bg = Bt + (size_t)(nBlk + stR) * K + stC;
  UST* aL = a_s + w * 512;   // wave-uniform LDS base (bytes w*1024)
  UST* bL = b_s + w * 512;
  size_t radv = (size_t)64 * K;

  for (int k0 = 0; k0 < K; k0 += 32) {
    __syncthreads();
    gl_lds16(Ag, aL);
    gl_lds16(Ag + radv, aL + 2048);
    gl_lds16(Bg, bL);
    gl_lds16(Bg + radv, bL + 2048);
    Ag += 32; Bg += 32;
    __syncthreads();
    v8bf af[4], bfv[4];
#pragma unroll
    for (int mt = 0; mt < 4; ++mt)
      af[mt] = *(const v8bf*)&a_s[(wr * 64 + mt * 16 + lr) * 32 + lg * 8];
#pragma unroll
    for (int nt = 0; nt < 4; ++nt)
      bfv[nt] = *(const v8bf*)&b_s[(wc * 64 + nt * 16 + lr) * 32 + lg * 8];
#pragma unroll
    for (int mt = 0; mt < 4; ++mt)
#pragma unroll
      for (int nt = 0; nt < 4; ++nt)
        acc[mt][nt] = __builtin_amdgcn_mfma_f32_16x16x32_bf16(af[mt], bfv[nt],
                                                              acc[mt][nt], 0, 0, 0);
  }

  // C/D layout: col = lane&15, row = 4*(lane>>4)+reg
  int row0 = mBlk + wr * 64 + lg * 4;
  int col0 = nBlk + wc * 64 + lr;
#pragma unroll
  for (int mt = 0; mt < 4; ++mt)
#pragma unroll
    for (int nt = 0; nt < 4; ++nt)
#pragma unroll
      for (int r = 0; r < 4; ++r) {
        int row = row0 + mt * 16 + r;
        int col = col0 + nt * 16;
        if constexpr (EPI == 0) {
          ((UST*)Cv)[(size_t)row * N + col] = f2b(acc[mt][nt][r]);
        } else {
          ((float*)Cv)[(size_t)row * N + col] = acc[mt][nt][r] + bias[col];
        }
      }
}

// ---------------- RoPE on q,k (q pre-scaled by 1/sqrt(64)) ----------------
__global__ __launch_bounds__(256) void k_rope(const UST* __restrict__ qkv,
                                              const float* __restrict__ cosT,
                                              const float* __restrict__ sinT,
                                              UST* __restrict__ qh,
                                              UST* __restrict__ kh) {
  int idx = blockIdx.x * 256 + threadIdx.x;  // B*L*40*32 = 5242880 exact
  int d = idx & 31;
  int hh = (idx >> 5) % 40;
  int row = idx / 1280;  // b*2048 + l
  int l = row & 2047, b = row >> 11;
  int col = (hh < 32) ? hh * 64 : 2048 + (hh - 32) * 64;
  float t1 = b2f(qkv[(size_t)row * 3072 + col + d]);
  float t2 = b2f(qkv[(size_t)row * 3072 + col + d + 32]);
  float c = cosT[l * 64 + d], s = sinT[l * 64 + d];
  float o1 = t1 * c - t2 * s;
  float o2 = t2 * c + t1 * s;
  if (hh < 32) {
    size_t base = (((size_t)b * 32 + hh) * 2048 + l) * 64 + d;
    qh[base] = f2b(o1 * 0.125f);
    qh[base + 32] = f2b(o2 * 0.125f);
  } else {
    size_t base = (((size_t)b * 8 + (hh - 32)) * 2048 + l) * 64 + d;
    kh[base] = f2b(o1);
    kh[base + 32] = f2b(o2);
  }
}

// ---------------- V transpose: qkv v-slice -> vt [B][8][64][L] ----------------
__global__ __launch_bounds__(256) void k_vtrans(const UST* __restrict__ qkv,
                                                UST* __restrict__ vt) {
  __shared__ __align__(16) UST tl[64][72];
  int lt = blockIdx.x, bg = blockIdx.y;
  int b = bg >> 3, g = bg & 7;
  int t = threadIdx.x;
  int li = t >> 2, d0 = (t & 3) * 16;
  const UST* src = qkv + (size_t)(b * 2048 + lt * 64 + li) * 3072 + 2560 + g * 64 + d0;
  *(uint4*)&tl[li][d0] = *(const uint4*)src;
  *(uint4*)&tl[li][d0 + 8] = *(const uint4*)(src + 8);
  __syncthreads();
  int d = t >> 2, l0 = (t & 3) * 16;
  union { UST u[8]; uint4 v; } r0, r1;
#pragma unroll
  for (int e = 0; e < 8; ++e) r0.u[e] = tl[l0 + e][d];
#pragma unroll
  for (int e = 0; e < 8; ++e) r1.u[e] = tl[l0 + 8 + e][d];
  UST* dstp = vt + (size_t)((b * 8 + g) * 64 + d) * 2048 + (size_t)lt * 64 + l0;
  *(uint4*)dstp = r0.v;
  *(uint4*)(dstp + 8) = r1.v;
}

// ---------------- causal flash attention, QBLK=128, swapped QK^T ----------------
// grid (16, 32, 2), 4 waves; wave w owns q rows qt*128 + w*32 .. +31 (2 mt tiles).
// Swapped S^T = mfma(K, Q): lane holds q-row (mt*16+lr), kpos = kt*16+4*lg+r.
__global__ __launch_bounds__(256) void k_attn(const UST* __restrict__ qh,
                                              const UST* __restrict__ kh,
                                              const UST* __restrict__ vt,
                                              UST* __restrict__ outp) {
  __shared__ __align__(16) UST k_s[64 * 72];          // K tile [kpos][hd], pad->72
  __shared__ __align__(16) UST v_s[64 * 72];          // V^T tile [d][kpos], pad->72
  __shared__ __align__(16) UST p_s[4][16 * 72];       // per-wave P [16 q][64 k]
  int qt = (int)gridDim.x - 1 - (int)blockIdx.x;      // longest blocks first
  int h = blockIdx.y, b = blockIdx.z;
  int g = h >> 2;
  int tid = threadIdx.x, w = tid >> 6, lane = tid & 63;
  int lr = lane & 15, lg = lane >> 4;
  int qbase = qt * 128 + w * 32;

  // Q B-frags (pre-scaled by 1/8): col=lr (q row), k=8*lg+e
  v8bf qf[2][2];
#pragma unroll
  for (int mt = 0; mt < 2; ++mt) {
    const UST* qp = qh + ((size_t)(b * 32 + h) * 2048 + qbase + mt * 16 + lr) * 64 + lg * 8;
    qf[mt][0] = *(const v8bf*)qp;
    qf[mt][1] = *(const v8bf*)(qp + 32);
  }

  float m[2] = {-1e30f, -1e30f}, lsum[2] = {0.f, 0.f};
  v4f o[2][4];
#pragma unroll
  for (int mt = 0; mt < 2; ++mt)
#pragma unroll
    for (int dt = 0; dt < 4; ++dt) o[mt][dt] = (v4f){0.f, 0.f, 0.f, 0.f};

  int sr = tid >> 2, sc = (tid & 3) * 16;
  const UST* kp0 = kh + ((size_t)(b * 8 + g) * 2048 + sr) * 64 + sc;
  const UST* vp0 = vt + ((size_t)(b * 8 + g) * 64 + sr) * 2048 + sc;
  UST* ksw = &k_s[sr * 72 + sc];
  UST* vsw = &v_s[sr * 72 + sc];

  // stage tile 0
  *(uint4*)ksw = *(const uint4*)kp0;
  *(uint4*)(ksw + 8) = *(const uint4*)(kp0 + 8);
  *(uint4*)vsw = *(const uint4*)vp0;
  *(uint4*)(vsw + 8) = *(const uint4*)(vp0 + 8);

  int jmax = 2 * qt + 1;
  for (int j = 0; j <= jmax; ++j) {
    __syncthreads();
    uint4 pk0, pk1, pv0, pv1;
    bool pref = (j < jmax);
    if (pref) {  // register-prefetch next tile; latency hides under compute
      const UST* kp = kp0 + (size_t)(j + 1) * 4096;
      pk0 = *(const uint4*)kp; pk1 = *(const uint4*)(kp + 8);
      const UST* vp = vp0 + (size_t)(j + 1) * 64;
      pv0 = *(const uint4*)vp; pv1 = *(const uint4*)(vp + 8);
    }
    if (j * 64 <= qbase + 31) {  // wave has unmasked work in this tile
      // S^T = K * Q^T
      v4f st[2][4];
#pragma unroll
      for (int kt = 0; kt < 4; ++kt) {
        v8bf kf0 = *(const v8bf*)&k_s[(kt * 16 + lr) * 72 + lg * 8];
        v8bf kf1 = *(const v8bf*)&k_s[(kt * 16 + lr) * 72 + 32 + lg * 8];
#pragma unroll
        for (int mt = 0; mt < 2; ++mt) {
          v4f z = (v4f){0.f, 0.f, 0.f, 0.f};
          z = __builtin_amdgcn_mfma_f32_16x16x32_bf16(kf0, qf[mt][0], z, 0, 0, 0);
          z = __builtin_amdgcn_mfma_f32_16x16x32_bf16(kf1, qf[mt][1], z, 0, 0, 0);
          st[mt][kt] = z;
        }
      }
      if (j * 64 + 63 > qbase) {  // diagonal region: causal mask
#pragma unroll
        for (int mt = 0; mt < 2; ++mt) {
          int qg = qbase + mt * 16 + lr;
#pragma unroll
          for (int kt = 0; kt < 4; ++kt)
#pragma unroll
            for (int r = 0; r < 4; ++r) {
              int kg = j * 64 + kt * 16 + 4 * lg + r;
              if (kg > qg) st[mt][kt][r] = -1e30f;
            }
        }
      }
#pragma unroll
      for (int mt = 0; mt < 2; ++mt) {
        // row max: in-lane tree over 16 + cross-lg shuffles
        float a0 = fmaxf(fmaxf(st[mt][0][0], st[mt][0][1]), fmaxf(st[mt][0][2], st[mt][0][3]));
        float a1 = fmaxf(fmaxf(st[mt][1][0], st[mt][1][1]), fmaxf(st[mt][1][2], st[mt][1][3]));
        float a2 = fmaxf(fmaxf(st[mt][2][0], st[mt][2][1]), fmaxf(st[mt][2][2], st[mt][2][3]));
        float a3 = fmaxf(fmaxf(st[mt][3][0], st[mt][3][1]), fmaxf(st[mt][3][2], st[mt][3][3]));
        float mx = fmaxf(fmaxf(a0, a1), fmaxf(a2, a3));
        mx = fmaxf(mx, __shfl_xor(mx, 16));
        mx = fmaxf(mx, __shfl_xor(mx, 32));
        float mn = fmaxf(m[mt], mx);
        float al = __expf(m[mt] - mn);
        m[mt] = mn;
        float rs = 0.f;
#pragma unroll
        for (int kt = 0; kt < 4; ++kt)
#pragma unroll
          for (int r = 0; r < 4; ++r) {
            float p = __expf(st[mt][kt][r] - mn);
            st[mt][kt][r] = p;
            rs += p;
          }
        rs += __shfl_xor(rs, 16);
        rs += __shfl_xor(rs, 32);
        lsum[mt] = lsum[mt] * al + rs;
        // rescale O (O rows live at 4*lg+r; alpha lives at lane lr=row)
#pragma unroll
        for (int r = 0; r < 4; ++r) {
          float ar = __shfl(al, 4 * lg + r);
          o[mt][0][r] *= ar; o[mt][1][r] *= ar;
          o[mt][2][r] *= ar; o[mt][3][r] *= ar;
        }
        // P rows for this mt -> LDS (wave-private, packed b64 writes)
        UST* pw = &p_s[w][lr * 72 + 4 * lg];
#pragma unroll
        for (int kt = 0; kt < 4; ++kt) {
          uint2 q2;
          q2.x = (uint32_t)f2b(st[mt][kt][0]) | ((uint32_t)f2b(st[mt][kt][1]) << 16);
          q2.y = (uint32_t)f2b(st[mt][kt][2]) | ((uint32_t)f2b(st[mt][kt][3]) << 16);
          *(uint2*)(pw + kt * 16) = q2;
        }
        // PV for this mt
#pragma unroll
        for (int kk = 0; kk < 2; ++kk) {
          v8bf pa = *(const v8bf*)&p_s[w][lr * 72 + kk * 32 + lg * 8];
#pragma unroll
          for (int dt = 0; dt < 4; ++dt) {
            v8bf vb = *(const v8bf*)&v_s[(dt * 16 + lr) * 72 + kk * 32 + lg * 8];
            o[mt][dt] = __builtin_amdgcn_mfma_f32_16x16x32_bf16(pa, vb, o[mt][dt], 0, 0, 0);
          }
        }
      }
    }
    __syncthreads();
    if (pref) {
      *(uint4*)ksw = pk0; *(uint4*)(ksw + 8) = pk1;
      *(uint4*)vsw = pv0; *(uint4*)(vsw + 8) = pv1;
    }
  }

  // epilogue: normalize (lsum at lane lr=row -> rows 4*lg+r) and store
#pragma unroll
  for (int mt = 0; mt < 2; ++mt) {
    float iv = 1.f / lsum[mt];
#pragma unroll
    for (int r = 0; r < 4; ++r) {
      float ivr = __shfl(iv, 4 * lg + r);
      size_t rowb = ((size_t)b * 2048 + qbase + mt * 16 + 4 * lg + r) * 2048 + h * 64 + lr;
#pragma unroll
      for (int dt = 0; dt < 4; ++dt)
        outp[rowb + dt * 16] = f2b(o[mt][dt][r] * ivr);
    }
  }
}

// ---------------- launch ----------------
extern "C" void kernel_launch(void* const* d_in, const int* in_sizes, int n_in,
                              void* d_out, int out_size, void* d_ws, size_t ws_size,
                              hipStream_t stream) {
  const float* x    = (const float*)d_in[0];
  const float* cosT = (const float*)d_in[2];
  const float* sinT = (const float*)d_in[3];
  const float* Wq   = (const float*)d_in[4];
  const float* Wk   = (const float*)d_in[5];
  const float* Wv   = (const float*)d_in[6];
  const float* Wo   = (const float*)d_in[7];
  const float* bo   = (const float*)d_in[8];
  float* out = (float*)d_out;

  char* ws = (char*)d_ws;
  UST* xb   = (UST*)(ws);                       // 16777216 B
  UST* wcat = (UST*)(ws + 16777216);            // 12582912 B
  UST* wot  = (UST*)(ws + 29360128);            //  8388608 B
  UST* qkv  = (UST*)(ws + 37748736);            // 25165824 B
  UST* qhp  = (UST*)(ws + 62914560);            // 16777216 B
  UST* khp  = (UST*)(ws + 79691776);            //  4194304 B
  UST* vtp  = (UST*)(ws + 83886080);            //  4194304 B
  UST* attn_o = xb;  // xb dead after QKV GEMM

  k_cast<<<4096, 256, 0, stream>>>(x, xb);
  k_castT<<<dim3(64, 64), dim3(32, 8), 0, stream>>>(Wq, wcat, 2048, 2048);
  k_castT<<<dim3(16, 64), dim3(32, 8), 0, stream>>>(Wk, wcat + (size_t)2048 * 2048, 512, 2048);
  k_castT<<<dim3(16, 64), dim3(32, 8), 0, stream>>>(Wv, wcat + (size_t)2560 * 2048, 512, 2048);
  k_castT<<<dim3(64, 64), dim3(32, 8), 0, stream>>>(Wo, wot, 2048, 2048);

  k_gemm<0><<<dim3(24, 32), 256, 0, stream>>>(xb, wcat, qkv, nullptr, 4096, 3072, 2048);
  k_rope<<<20480, 256, 0, stream>>>(qkv, cosT, sinT, qhp, khp);
  k_vtrans<<<dim3(32, 16), 256, 0, stream>>>(qkv, vtp);
  k_attn<<<dim3(16, 32, 2), 256, 0, stream>>>(qhp, khp, vtp, attn_o);
  k_gemm<1><<<dim3(16, 32), 256, 0, stream>>>(attn_o, wot, out, bo, 4096, 2048, 2048);
}

// Round 3
// 227.691 us; speedup vs baseline: 1.7740x; 1.4321x over previous
//
#include <hip/hip_runtime.h>
#include <cstdint>

typedef unsigned short UST;
typedef __bf16 v8bf __attribute__((ext_vector_type(8)));
typedef float v4f __attribute__((ext_vector_type(4)));

static __device__ __forceinline__ UST f2b(float f) {
  union { float f; uint32_t u; } c; c.f = f;
  uint32_t u = c.u;
  u += 0x7fffu + ((u >> 16) & 1u);   // RNE
  return (UST)(u >> 16);
}
static __device__ __forceinline__ float b2f(UST h) {
  union { uint32_t u; float f; } c; c.u = ((uint32_t)h) << 16;
  return c.f;
}
static __device__ __forceinline__ uint32_t cvtpk(float lo, float hi) {
  uint32_t r;
  asm("v_cvt_pk_bf16_f32 %0, %1, %2" : "=v"(r) : "v"(lo), "v"(hi));
  return r;
}
static __device__ __forceinline__ float fexp2(float x) {  // 2^x
  float r;
  asm("v_exp_f32 %0, %1" : "=v"(r) : "v"(x));
  return r;
}

// async global->LDS, 16B per lane
static __device__ __forceinline__ void gl_lds16(const UST* g, UST* l) {
  __builtin_amdgcn_global_load_lds(
      (const __attribute__((address_space(1))) void*)g,
      (__attribute__((address_space(3))) void*)l, 16, 0, 0);
}

// ---------------- cast x f32 -> bf16, 8 elems/thread ----------------
__global__ __launch_bounds__(256) void k_cast(const float* __restrict__ src,
                                              UST* __restrict__ dst) {
  size_t i = (size_t)blockIdx.x * 256 + threadIdx.x;
  const float4* s4 = reinterpret_cast<const float4*>(src) + 2 * i;
  float4 a = s4[0], b = s4[1];
  union { UST s[8]; uint4 v; } r;
  r.s[0] = f2b(a.x); r.s[1] = f2b(a.y); r.s[2] = f2b(a.z); r.s[3] = f2b(a.w);
  r.s[4] = f2b(b.x); r.s[5] = f2b(b.y); r.s[6] = f2b(b.z); r.s[7] = f2b(b.w);
  reinterpret_cast<uint4*>(dst)[i] = r.v;
}

// ------------- transpose+cast: W [K][N] f32 -> dst [N][K] bf16 -------------
__global__ __launch_bounds__(256) void k_castT(const float* __restrict__ W,
                                               UST* __restrict__ dst, int N, int K) {
  __shared__ float tile[32][33];
  int nt = blockIdx.x * 32, kt = blockIdx.y * 32;
  int tx = threadIdx.x, ty = threadIdx.y;  // 32 x 8
#pragma unroll
  for (int r = 0; r < 4; ++r)
    tile[ty + r * 8][tx] = W[(size_t)(kt + ty + r * 8) * N + nt + tx];
  __syncthreads();
#pragma unroll
  for (int r = 0; r < 4; ++r)
    dst[(size_t)(nt + ty + r * 8) * K + kt + tx] = f2b(tile[tx][ty + r * 8]);
}

// ---------------- bf16 GEMM (m97 structure): C = A * Bt^T ----------------
template <int EPI>
__global__ __launch_bounds__(256) void k_gemm(const UST* __restrict__ A,
                                              const UST* __restrict__ Bt,
                                              void* __restrict__ Cv,
                                              const float* __restrict__ bias,
                                              int M, int N, int K) {
  __shared__ __align__(16) UST a_s[128 * 32];
  __shared__ __align__(16) UST b_s[128 * 32];
  int tid = threadIdx.x;
  int lane = tid & 63, w = tid >> 6;
  int lr = lane & 15, lg = lane >> 4;
  int wr = w >> 1, wc = w & 1;
  int mBlk = blockIdx.y * 128, nBlk = blockIdx.x * 128;

  v4f acc[4][4];
#pragma unroll
  for (int i = 0; i < 4; ++i)
#pragma unroll
    for (int j = 0; j < 4; ++j) acc[i][j] = (v4f){0.f, 0.f, 0.f, 0.f};

  int stR = tid >> 2, stC = (tid & 3) * 8;
  const UST* Ag = A + (size_t)(mBlk + stR) * K + stC;
  const UST* Bg = Bt + (size_t)(nBlk + stR) * K + stC;
  UST* aL = a_s + w * 512;
  UST* bL = b_s + w * 512;
  size_t radv = (size_t)64 * K;

  for (int k0 = 0; k0 < K; k0 += 32) {
    __syncthreads();
    gl_lds16(Ag, aL);
    gl_lds16(Ag + radv, aL + 2048);
    gl_lds16(Bg, bL);
    gl_lds16(Bg + radv, bL + 2048);
    Ag += 32; Bg += 32;
    __syncthreads();
    v8bf af[4], bfv[4];
#pragma unroll
    for (int mt = 0; mt < 4; ++mt)
      af[mt] = *(const v8bf*)&a_s[(wr * 64 + mt * 16 + lr) * 32 + lg * 8];
#pragma unroll
    for (int nt = 0; nt < 4; ++nt)
      bfv[nt] = *(const v8bf*)&b_s[(wc * 64 + nt * 16 + lr) * 32 + lg * 8];
#pragma unroll
    for (int mt = 0; mt < 4; ++mt)
#pragma unroll
      for (int nt = 0; nt < 4; ++nt)
        acc[mt][nt] = __builtin_amdgcn_mfma_f32_16x16x32_bf16(af[mt], bfv[nt],
                                                              acc[mt][nt], 0, 0, 0);
  }

  int row0 = mBlk + wr * 64 + lg * 4;
  int col0 = nBlk + wc * 64 + lr;
#pragma unroll
  for (int mt = 0; mt < 4; ++mt)
#pragma unroll
    for (int nt = 0; nt < 4; ++nt)
#pragma unroll
      for (int r = 0; r < 4; ++r) {
        int row = row0 + mt * 16 + r;
        int col = col0 + nt * 16;
        if constexpr (EPI == 0) {
          ((UST*)Cv)[(size_t)row * N + col] = f2b(acc[mt][nt][r]);
        } else {
          ((float*)Cv)[(size_t)row * N + col] = acc[mt][nt][r] + bias[col];
        }
      }
}

// ---------------- RoPE on q,k (q pre-scaled by 1/sqrt(64)) ----------------
__global__ __launch_bounds__(256) void k_rope(const UST* __restrict__ qkv,
                                              const float* __restrict__ cosT,
                                              const float* __restrict__ sinT,
                                              UST* __restrict__ qh,
                                              UST* __restrict__ kh) {
  int idx = blockIdx.x * 256 + threadIdx.x;
  int d = idx & 31;
  int hh = (idx >> 5) % 40;
  int row = idx / 1280;
  int l = row & 2047, b = row >> 11;
  int col = (hh < 32) ? hh * 64 : 2048 + (hh - 32) * 64;
  float t1 = b2f(qkv[(size_t)row * 3072 + col + d]);
  float t2 = b2f(qkv[(size_t)row * 3072 + col + d + 32]);
  float c = cosT[l * 64 + d], s = sinT[l * 64 + d];
  float o1 = t1 * c - t2 * s;
  float o2 = t2 * c + t1 * s;
  if (hh < 32) {
    size_t base = (((size_t)b * 32 + hh) * 2048 + l) * 64 + d;
    qh[base] = f2b(o1 * 0.125f);
    qh[base + 32] = f2b(o2 * 0.125f);
  } else {
    size_t base = (((size_t)b * 8 + (hh - 32)) * 2048 + l) * 64 + d;
    kh[base] = f2b(o1);
    kh[base + 32] = f2b(o2);
  }
}

// ---------------- V transpose: qkv v-slice -> vt [B][8][64][L] ----------------
__global__ __launch_bounds__(256) void k_vtrans(const UST* __restrict__ qkv,
                                                UST* __restrict__ vt) {
  __shared__ __align__(16) UST tl[64][72];
  int lt = blockIdx.x, bg = blockIdx.y;
  int b = bg >> 3, g = bg & 7;
  int t = threadIdx.x;
  int li = t >> 2, d0 = (t & 3) * 16;
  const UST* src = qkv + (size_t)(b * 2048 + lt * 64 + li) * 3072 + 2560 + g * 64 + d0;
  *(uint4*)&tl[li][d0] = *(const uint4*)src;
  *(uint4*)&tl[li][d0 + 8] = *(const uint4*)(src + 8);
  __syncthreads();
  int d = t >> 2, l0 = (t & 3) * 16;
  union { UST u[8]; uint4 v; } r0, r1;
#pragma unroll
  for (int e = 0; e < 8; ++e) r0.u[e] = tl[l0 + e][d];
#pragma unroll
  for (int e = 0; e < 8; ++e) r1.u[e] = tl[l0 + 8 + e][d];
  UST* dstp = vt + (size_t)((b * 8 + g) * 64 + d) * 2048 + (size_t)lt * 64 + l0;
  *(uint4*)dstp = r0.v;
  *(uint4*)(dstp + 8) = r1.v;
}

// ---------------- causal flash attention: balanced pairs, KVBLK=128 ----------------
// grid (8, 32, 2), 8 waves x 16 q-rows. Block handles q-tiles bx and 15-bx
// (QBLK=128 each) -> exactly 17 KV-iterations per block; 512 blocks = 2/CU
// all co-resident. Swapped S^T = mfma(K, Q): lane holds q-row lr,
// kpos = kt*16 + 4*lg + r.
__global__ __launch_bounds__(512, 4) void k_attn(const UST* __restrict__ qh,
                                                 const UST* __restrict__ kh,
                                                 const UST* __restrict__ vt,
                                                 UST* __restrict__ outp) {
  __shared__ __align__(16) UST k_s[128 * 72];       // K tile [kpos][64], pad->72
  __shared__ __align__(16) UST v_s[64 * 136];       // V^T tile [d][128], pad->136
  __shared__ __align__(16) UST p_s[8][16 * 136];    // per-wave P [16 q][128 k]
  int bx = blockIdx.x, h = blockIdx.y, b = blockIdx.z;
  int g = h >> 2;
  int tid = threadIdx.x, w = tid >> 6, lane = tid & 63;
  int lr = lane & 15, lg = lane >> 4;

  // staging coords (512 threads): K 128x64, V^T 64x128, 16 elems/thread
  int ksr = tid >> 2, ksc = (tid & 3) * 16;
  int vsr = tid >> 3, vsc = (tid & 7) * 16;
  const UST* kbase = kh + ((size_t)(b * 8 + g) * 2048 + ksr) * 64 + ksc;
  const UST* vbase = vt + ((size_t)(b * 8 + g) * 64 + vsr) * 2048 + vsc;
  UST* kdst = &k_s[ksr * 72 + ksc];
  UST* vdst = &v_s[vsr * 136 + vsc];

  for (int half = 0; half < 2; ++half) {
    int qt = half ? (15 - bx) : bx;
    int qbase = qt * 128 + w * 16;

    const UST* qp = qh + ((size_t)(b * 32 + h) * 2048 + qbase + lr) * 64 + lg * 8;
    v8bf qf0 = *(const v8bf*)qp;
    v8bf qf1 = *(const v8bf*)(qp + 32);

    float m = -1e30f, ls = 0.f;
    v4f o[4];
#pragma unroll
    for (int dt = 0; dt < 4; ++dt) o[dt] = (v4f){0.f, 0.f, 0.f, 0.f};

    __syncthreads();  // prior half's tile reads complete
    uint4 pk0 = *(const uint4*)kbase, pk1 = *(const uint4*)(kbase + 8);
    uint4 pv0 = *(const uint4*)vbase, pv1 = *(const uint4*)(vbase + 8);
    *(uint4*)kdst = pk0; *(uint4*)(kdst + 8) = pk1;
    *(uint4*)vdst = pv0; *(uint4*)(vdst + 8) = pv1;

    for (int j = 0; j <= qt; ++j) {
      __syncthreads();  // staged tile visible
      bool pref = (j < qt);
      if (pref) {  // register-prefetch next tile; hides under compute
        const UST* kg = kbase + (size_t)(j + 1) * 8192;
        const UST* vg = vbase + (j + 1) * 128;
        pk0 = *(const uint4*)kg; pk1 = *(const uint4*)(kg + 8);
        pv0 = *(const uint4*)vg; pv1 = *(const uint4*)(vg + 8);
      }

      // S^T = K * Q^T : 16 MFMAs
      v4f st[8];
#pragma unroll
      for (int kt = 0; kt < 8; ++kt) {
        const UST* kr = &k_s[(kt * 16 + lr) * 72 + lg * 8];
        v8bf kf0 = *(const v8bf*)kr;
        v8bf kf1 = *(const v8bf*)(kr + 32);
        v4f z = (v4f){0.f, 0.f, 0.f, 0.f};
        z = __builtin_amdgcn_mfma_f32_16x16x32_bf16(kf0, qf0, z, 0, 0, 0);
        z = __builtin_amdgcn_mfma_f32_16x16x32_bf16(kf1, qf1, z, 0, 0, 0);
        st[kt] = z;
      }
      if (j == qt) {  // diagonal: causal mask
        int qg = qbase + lr;
#pragma unroll
        for (int kt = 0; kt < 8; ++kt)
#pragma unroll
          for (int r = 0; r < 4; ++r) {
            int kg2 = j * 128 + kt * 16 + 4 * lg + r;
            if (kg2 > qg) st[kt][r] = -1e30f;
          }
      }

      // row max (row = lr, spread over 4 lg lanes)
      float t0 = fmaxf(fmaxf(st[0][0], st[0][1]), fmaxf(st[0][2], st[0][3]));
      float t1 = fmaxf(fmaxf(st[1][0], st[1][1]), fmaxf(st[1][2], st[1][3]));
      float t2 = fmaxf(fmaxf(st[2][0], st[2][1]), fmaxf(st[2][2], st[2][3]));
      float t3 = fmaxf(fmaxf(st[3][0], st[3][1]), fmaxf(st[3][2], st[3][3]));
      float t4 = fmaxf(fmaxf(st[4][0], st[4][1]), fmaxf(st[4][2], st[4][3]));
      float t5 = fmaxf(fmaxf(st[5][0], st[5][1]), fmaxf(st[5][2], st[5][3]));
      float t6 = fmaxf(fmaxf(st[6][0], st[6][1]), fmaxf(st[6][2], st[6][3]));
      float t7 = fmaxf(fmaxf(st[7][0], st[7][1]), fmaxf(st[7][2], st[7][3]));
      float mx = fmaxf(fmaxf(fmaxf(t0, t1), fmaxf(t2, t3)),
                       fmaxf(fmaxf(t4, t5), fmaxf(t6, t7)));
      mx = fmaxf(mx, __shfl_xor(mx, 16));
      mx = fmaxf(mx, __shfl_xor(mx, 32));

      // defer-max (T13): rescale only when max grew past threshold
      if (!__all(mx <= m + 8.f)) {
        float mn = fmaxf(m, mx);
        float al = __expf(m - mn);
        m = mn;
        ls *= al;
#pragma unroll
        for (int r = 0; r < 4; ++r) {
          float ar = __shfl(al, 4 * lg + r);
          o[0][r] *= ar; o[1][r] *= ar; o[2][r] *= ar; o[3][r] *= ar;
        }
      }

      constexpr float LOG2E = 1.44269504f;
      float mlog = m * LOG2E;
      float rs = 0.f;
      UST* pw = &p_s[w][lr * 136 + 4 * lg];
#pragma unroll
      for (int kt = 0; kt < 8; ++kt) {
        float p0 = fexp2(__builtin_fmaf(st[kt][0], LOG2E, -mlog));
        float p1 = fexp2(__builtin_fmaf(st[kt][1], LOG2E, -mlog));
        float p2 = fexp2(__builtin_fmaf(st[kt][2], LOG2E, -mlog));
        float p3 = fexp2(__builtin_fmaf(st[kt][3], LOG2E, -mlog));
        rs += (p0 + p1) + (p2 + p3);
        uint2 q2;
        q2.x = cvtpk(p0, p1);
        q2.y = cvtpk(p2, p3);
        *(uint2*)(pw + kt * 16) = q2;
      }
      rs += __shfl_xor(rs, 16);
      rs += __shfl_xor(rs, 32);
      ls += rs;

      // PV: 16 MFMAs
#pragma unroll
      for (int kk = 0; kk < 4; ++kk) {
        v8bf pa = *(const v8bf*)&p_s[w][lr * 136 + kk * 32 + lg * 8];
#pragma unroll
        for (int dt = 0; dt < 4; ++dt) {
          v8bf vb = *(const v8bf*)&v_s[(dt * 16 + lr) * 136 + kk * 32 + lg * 8];
          o[dt] = __builtin_amdgcn_mfma_f32_16x16x32_bf16(pa, vb, o[dt], 0, 0, 0);
        }
      }

      __syncthreads();  // tile reads done
      if (pref) {
        *(uint4*)kdst = pk0; *(uint4*)(kdst + 8) = pk1;
        *(uint4*)vdst = pv0; *(uint4*)(vdst + 8) = pv1;
      }
    }

    // epilogue: normalize and store O as [B*L][H*64] bf16
    float iv = 1.f / ls;
#pragma unroll
    for (int r = 0; r < 4; ++r) {
      float ivr = __shfl(iv, 4 * lg + r);
      size_t rowb = ((size_t)b * 2048 + qbase + 4 * lg + r) * 2048 + h * 64 + lr;
#pragma unroll
      for (int dt = 0; dt < 4; ++dt)
        outp[rowb + dt * 16] = f2b(o[dt][r] * ivr);
    }
  }
}

// ---------------- launch ----------------
extern "C" void kernel_launch(void* const* d_in, const int* in_sizes, int n_in,
                              void* d_out, int out_size, void* d_ws, size_t ws_size,
                              hipStream_t stream) {
  const float* x    = (const float*)d_in[0];
  const float* cosT = (const float*)d_in[2];
  const float* sinT = (const float*)d_in[3];
  const float* Wq   = (const float*)d_in[4];
  const float* Wk   = (const float*)d_in[5];
  const float* Wv   = (const float*)d_in[6];
  const float* Wo   = (const float*)d_in[7];
  const float* bo   = (const float*)d_in[8];
  float* out = (float*)d_out;

  char* ws = (char*)d_ws;
  UST* xb   = (UST*)(ws);                       // 16777216 B
  UST* wcat = (UST*)(ws + 16777216);            // 12582912 B
  UST* wot  = (UST*)(ws + 29360128);            //  8388608 B
  UST* qkv  = (UST*)(ws + 37748736);            // 25165824 B
  UST* qhp  = (UST*)(ws + 62914560);            // 16777216 B
  UST* khp  = (UST*)(ws + 79691776);            //  4194304 B
  UST* vtp  = (UST*)(ws + 83886080);            //  4194304 B
  UST* attn_o = xb;  // xb dead after QKV GEMM

  k_cast<<<4096, 256, 0, stream>>>(x, xb);
  k_castT<<<dim3(64, 64), dim3(32, 8), 0, stream>>>(Wq, wcat, 2048, 2048);
  k_castT<<<dim3(16, 64), dim3(32, 8), 0, stream>>>(Wk, wcat + (size_t)2048 * 2048, 512, 2048);
  k_castT<<<dim3(16, 64), dim3(32, 8), 0, stream>>>(Wv, wcat + (size_t)2560 * 2048, 512, 2048);
  k_castT<<<dim3(64, 64), dim3(32, 8), 0, stream>>>(Wo, wot, 2048, 2048);

  k_gemm<0><<<dim3(24, 32), 256, 0, stream>>>(xb, wcat, qkv, nullptr, 4096, 3072, 2048);
  k_rope<<<20480, 256, 0, stream>>>(qkv, cosT, sinT, qhp, khp);
  k_vtrans<<<dim3(32, 16), 256, 0, stream>>>(qkv, vtp);
  k_attn<<<dim3(8, 32, 2), 512, 0, stream>>>(qhp, khp, vtp, attn_o);
  k_gemm<1><<<dim3(16, 32), 256, 0, stream>>>(attn_o, wot, out, bo, 4096, 2048, 2048);
}

// Round 4
// 219.638 us; speedup vs baseline: 1.8390x; 1.0367x over previous
//
#include <hip/hip_runtime.h>
#include <cstdint>

typedef unsigned short UST;
typedef __bf16 v8bf __attribute__((ext_vector_type(8)));
typedef float v4f __attribute__((ext_vector_type(4)));

static __device__ __forceinline__ UST f2b(float f) {
  union { float f; uint32_t u; } c; c.f = f;
  uint32_t u = c.u;
  u += 0x7fffu + ((u >> 16) & 1u);   // RNE
  return (UST)(u >> 16);
}
static __device__ __forceinline__ float b2f(UST h) {
  union { uint32_t u; float f; } c; c.u = ((uint32_t)h) << 16;
  return c.f;
}
static __device__ __forceinline__ uint32_t cvtpk(float lo, float hi) {
  uint32_t r;
  asm("v_cvt_pk_bf16_f32 %0, %1, %2" : "=v"(r) : "v"(lo), "v"(hi));
  return r;
}
static __device__ __forceinline__ float fexp2(float x) {  // 2^x
  float r;
  asm("v_exp_f32 %0, %1" : "=v"(r) : "v"(x));
  return r;
}
template <int N>
static __device__ __forceinline__ void wait_vm() {
  asm volatile("s_waitcnt vmcnt(%0)" :: "i"(N));
}

// async global->LDS, 16B per lane
static __device__ __forceinline__ void gl_lds16(const UST* g, UST* l) {
  __builtin_amdgcn_global_load_lds(
      (const __attribute__((address_space(1))) void*)g,
      (__attribute__((address_space(3))) void*)l, 16, 0, 0);
}

// ---------------- cast x f32 -> bf16, 8 elems/thread ----------------
__global__ __launch_bounds__(256) void k_cast(const float* __restrict__ src,
                                              UST* __restrict__ dst) {
  size_t i = (size_t)blockIdx.x * 256 + threadIdx.x;
  const float4* s4 = reinterpret_cast<const float4*>(src) + 2 * i;
  float4 a = s4[0], b = s4[1];
  union { UST s[8]; uint4 v; } r;
  r.s[0] = f2b(a.x); r.s[1] = f2b(a.y); r.s[2] = f2b(a.z); r.s[3] = f2b(a.w);
  r.s[4] = f2b(b.x); r.s[5] = f2b(b.y); r.s[6] = f2b(b.z); r.s[7] = f2b(b.w);
  reinterpret_cast<uint4*>(dst)[i] = r.v;
}

// ------------- transpose+cast: W [K][N] f32 -> dst [N][K] bf16 -------------
__global__ __launch_bounds__(256) void k_castT(const float* __restrict__ W,
                                               UST* __restrict__ dst, int N, int K) {
  __shared__ float tile[32][33];
  int nt = blockIdx.x * 32, kt = blockIdx.y * 32;
  int tx = threadIdx.x, ty = threadIdx.y;  // 32 x 8
#pragma unroll
  for (int r = 0; r < 4; ++r)
    tile[ty + r * 8][tx] = W[(size_t)(kt + ty + r * 8) * N + nt + tx];
  __syncthreads();
#pragma unroll
  for (int r = 0; r < 4; ++r)
    dst[(size_t)(nt + ty + r * 8) * K + kt + tx] = f2b(tile[tx][ty + r * 8]);
}

// ============ 8-phase counted-vmcnt GEMM: C[M][N] = A[M][K] * Bt[N][K]^T ============
// BM x BN tile, BK=64 (two 32-k slices), 512 thr = 8 waves (WM x WN of BM/WM x BN/WN).
// LDS: k-split halves, 64B rows (bank-uniform b128 frag reads, no swizzle needed).
// Double-buffered; stages for K-tile kt+1 issued across kt's 4 phases; counted vmcnt
// (keep = 2*CA+CB) at phases 0,2 -- never drained to 0 in the main loop (T4).
// Phase: [stage-issue][vmcnt][barrier][ds_read][setprio1 MFMA setprio0][barrier] (T3+T5).
template <int BM, int BN, int WM, int WN, int EPI>
__global__ __launch_bounds__(512, 2) void k_gemm2(const UST* __restrict__ A,
                                                  const UST* __restrict__ Bt,
                                                  void* __restrict__ Cv,
                                                  const float* __restrict__ bias,
                                                  int M, int N, int K, int ntn) {
  constexpr int WMR = BM / WM, WNR = BN / WN;
  constexpr int MF = WMR / 16, NF = WNR / 16, MH = MF / 2;
  constexpr int CA = BM / 128, CB = BN / 128;     // gl_lds calls per half
  constexpr int NKEEP = 2 * CA + CB;              // steady counted-vmcnt
  constexpr int AELEMS = 4 * BM * 32;             // 2buf x 2slice x BM x 32
  __shared__ __align__(16) UST lds[AELEMS + 4 * BN * 32];

  int tid = threadIdx.x, w = tid >> 6, lane = tid & 63;
  int lr = lane & 15, lg = lane >> 4;
  int wm = w / WN, wn = w % WN;

  // bijective XCD swizzle (grid % 8 == 0 for both instantiations)
  int T = (int)gridDim.x;
  int q = T >> 3;
  int bid = (int)blockIdx.x;
  int swz = (bid & 7) * q + (bid >> 3);
  int mBlk = (swz / ntn) * BM, nBlk = (swz % ntn) * BN;

  v4f acc[MF][NF];
#pragma unroll
  for (int i = 0; i < MF; ++i)
#pragma unroll
    for (int j = 0; j < NF; ++j) acc[i][j] = (v4f){0.f, 0.f, 0.f, 0.f};

  // staging: thread t covers bytes t*16 of each 8KB chunk: row t/4, elems (t&3)*8
  int srow = tid >> 2, scol = (tid & 3) * 8;
  const UST* Abase = A + (size_t)(mBlk + srow) * K + scol;
  const UST* Bbase = Bt + (size_t)(nBlk + srow) * K + scol;
  int ldsW = w * 512;  // wave-uniform chunk base (elems)

  auto stageA = [&](int buf, int s, int kt) {
#pragma unroll
    for (int i = 0; i < CA; ++i)
      gl_lds16(Abase + (size_t)(i * 128) * K + kt * 64 + s * 32,
               &lds[(buf * 2 + s) * BM * 32 + i * 4096 + ldsW]);
  };
  auto stageB = [&](int buf, int s, int kt) {
#pragma unroll
    for (int i = 0; i < CB; ++i)
      gl_lds16(Bbase + (size_t)(i * 128) * K + kt * 64 + s * 32,
               &lds[AELEMS + (buf * 2 + s) * BN * 32 + i * 4096 + ldsW]);
  };
  auto ldA = [&](int buf, int s, int mh, int f) -> v8bf {
    int row = wm * WMR + mh * (WMR / 2) + f * 16 + lr;
    return *(const v8bf*)&lds[((buf * 2 + s) * BM + row) * 32 + lg * 8];
  };
  auto ldB = [&](int buf, int s, int nf) -> v8bf {
    int row = wn * WNR + nf * 16 + lr;
    return *(const v8bf*)&lds[AELEMS + ((buf * 2 + s) * BN + row) * 32 + lg * 8];
  };

  int NT = K >> 6;  // K-tiles of 64
  // prologue: tile 0, issue order As0, Bs0, As1, Bs1 (matches steady-state order)
  stageA(0, 0, 0); stageB(0, 0, 0); stageA(0, 1, 0); stageB(0, 1, 0);

  for (int kt = 0; kt < NT; ++kt) {
    int buf = kt & 1, nb = buf ^ 1;
    bool more = (kt + 1 < NT);
#pragma unroll
    for (int s = 0; s < 2; ++s) {
      // ---- phase (s, mh=0) ----
      if (more) {
        stageA(nb, s, kt + 1);
        wait_vm<NKEEP>();
      } else {
        if (s == 0) wait_vm<CA + CB>(); else wait_vm<0>();
      }
      __builtin_amdgcn_s_barrier();
      __builtin_amdgcn_sched_barrier(0);
      v8bf bfr[NF], afr[MH];
#pragma unroll
      for (int nf = 0; nf < NF; ++nf) bfr[nf] = ldB(buf, s, nf);
#pragma unroll
      for (int f = 0; f < MH; ++f) afr[f] = ldA(buf, s, 0, f);
      __builtin_amdgcn_s_setprio(1);
#pragma unroll
      for (int f = 0; f < MH; ++f)
#pragma unroll
        for (int nf = 0; nf < NF; ++nf)
          acc[f][nf] = __builtin_amdgcn_mfma_f32_16x16x32_bf16(afr[f], bfr[nf],
                                                               acc[f][nf], 0, 0, 0);
      __builtin_amdgcn_s_setprio(0);
      __builtin_amdgcn_s_barrier();
      // ---- phase (s, mh=1) ----
      if (more) stageB(nb, s, kt + 1);
      __builtin_amdgcn_s_barrier();
      __builtin_amdgcn_sched_barrier(0);
#pragma unroll
      for (int f = 0; f < MH; ++f) afr[f] = ldA(buf, s, 1, f);
      __builtin_amdgcn_s_setprio(1);
#pragma unroll
      for (int f = 0; f < MH; ++f)
#pragma unroll
        for (int nf = 0; nf < NF; ++nf)
          acc[MH + f][nf] = __builtin_amdgcn_mfma_f32_16x16x32_bf16(afr[f], bfr[nf],
                                                                    acc[MH + f][nf], 0, 0, 0);
      __builtin_amdgcn_s_setprio(0);
      __builtin_amdgcn_s_barrier();
    }
  }

  // epilogue: C/D layout col = lane&15, row = 4*(lane>>4)+reg
  int row0 = mBlk + wm * WMR + lg * 4;
  int col0 = nBlk + wn * WNR + lr;
#pragma unroll
  for (int fm = 0; fm < MF; ++fm)
#pragma unroll
    for (int nf = 0; nf < NF; ++nf)
#pragma unroll
      for (int r = 0; r < 4; ++r) {
        int row = row0 + fm * 16 + r;
        int col = col0 + nf * 16;
        if constexpr (EPI == 0) {
          ((UST*)Cv)[(size_t)row * N + col] = f2b(acc[fm][nf][r]);
        } else {
          ((float*)Cv)[(size_t)row * N + col] = acc[fm][nf][r] + bias[col];
        }
      }
}

// ---------------- RoPE on q,k (q pre-scaled by 1/sqrt(64)) ----------------
__global__ __launch_bounds__(256) void k_rope(const UST* __restrict__ qkv,
                                              const float* __restrict__ cosT,
                                              const float* __restrict__ sinT,
                                              UST* __restrict__ qh,
                                              UST* __restrict__ kh) {
  int idx = blockIdx.x * 256 + threadIdx.x;
  int d = idx & 31;
  int hh = (idx >> 5) % 40;
  int row = idx / 1280;
  int l = row & 2047, b = row >> 11;
  int col = (hh < 32) ? hh * 64 : 2048 + (hh - 32) * 64;
  float t1 = b2f(qkv[(size_t)row * 3072 + col + d]);
  float t2 = b2f(qkv[(size_t)row * 3072 + col + d + 32]);
  float c = cosT[l * 64 + d], s = sinT[l * 64 + d];
  float o1 = t1 * c - t2 * s;
  float o2 = t2 * c + t1 * s;
  if (hh < 32) {
    size_t base = (((size_t)b * 32 + hh) * 2048 + l) * 64 + d;
    qh[base] = f2b(o1 * 0.125f);
    qh[base + 32] = f2b(o2 * 0.125f);
  } else {
    size_t base = (((size_t)b * 8 + (hh - 32)) * 2048 + l) * 64 + d;
    kh[base] = f2b(o1);
    kh[base + 32] = f2b(o2);
  }
}

// ---------------- V transpose: qkv v-slice -> vt [B][8][64][L] ----------------
__global__ __launch_bounds__(256) void k_vtrans(const UST* __restrict__ qkv,
                                                UST* __restrict__ vt) {
  __shared__ __align__(16) UST tl[64][72];
  int lt = blockIdx.x, bg = blockIdx.y;
  int b = bg >> 3, g = bg & 7;
  int t = threadIdx.x;
  int li = t >> 2, d0 = (t & 3) * 16;
  const UST* src = qkv + (size_t)(b * 2048 + lt * 64 + li) * 3072 + 2560 + g * 64 + d0;
  *(uint4*)&tl[li][d0] = *(const uint4*)src;
  *(uint4*)&tl[li][d0 + 8] = *(const uint4*)(src + 8);
  __syncthreads();
  int d = t >> 2, l0 = (t & 3) * 16;
  union { UST u[8]; uint4 v; } r0, r1;
#pragma unroll
  for (int e = 0; e < 8; ++e) r0.u[e] = tl[l0 + e][d];
#pragma unroll
  for (int e = 0; e < 8; ++e) r1.u[e] = tl[l0 + 8 + e][d];
  UST* dstp = vt + (size_t)((b * 8 + g) * 64 + d) * 2048 + (size_t)lt * 64 + l0;
  *(uint4*)dstp = r0.v;
  *(uint4*)(dstp + 8) = r1.v;
}

// ---------------- causal flash attention: balanced pairs, KVBLK=128 ----------------
__global__ __launch_bounds__(512, 4) void k_attn(const UST* __restrict__ qh,
                                                 const UST* __restrict__ kh,
                                                 const UST* __restrict__ vt,
                                                 UST* __restrict__ outp) {
  __shared__ __align__(16) UST k_s[128 * 72];
  __shared__ __align__(16) UST v_s[64 * 136];
  __shared__ __align__(16) UST p_s[8][16 * 136];
  int bx = blockIdx.x, h = blockIdx.y, b = blockIdx.z;
  int g = h >> 2;
  int tid = threadIdx.x, w = tid >> 6, lane = tid & 63;
  int lr = lane & 15, lg = lane >> 4;

  int ksr = tid >> 2, ksc = (tid & 3) * 16;
  int vsr = tid >> 3, vsc = (tid & 7) * 16;
  const UST* kbase = kh + ((size_t)(b * 8 + g) * 2048 + ksr) * 64 + ksc;
  const UST* vbase = vt + ((size_t)(b * 8 + g) * 64 + vsr) * 2048 + vsc;
  UST* kdst = &k_s[ksr * 72 + ksc];
  UST* vdst = &v_s[vsr * 136 + vsc];

  for (int half = 0; half < 2; ++half) {
    int qt = half ? (15 - bx) : bx;
    int qbase = qt * 128 + w * 16;

    const UST* qp = qh + ((size_t)(b * 32 + h) * 2048 + qbase + lr) * 64 + lg * 8;
    v8bf qf0 = *(const v8bf*)qp;
    v8bf qf1 = *(const v8bf*)(qp + 32);

    float m = -1e30f, ls = 0.f;
    v4f o[4];
#pragma unroll
    for (int dt = 0; dt < 4; ++dt) o[dt] = (v4f){0.f, 0.f, 0.f, 0.f};

    __syncthreads();
    uint4 pk0 = *(const uint4*)kbase, pk1 = *(const uint4*)(kbase + 8);
    uint4 pv0 = *(const uint4*)vbase, pv1 = *(const uint4*)(vbase + 8);
    *(uint4*)kdst = pk0; *(uint4*)(kdst + 8) = pk1;
    *(uint4*)vdst = pv0; *(uint4*)(vdst + 8) = pv1;

    for (int j = 0; j <= qt; ++j) {
      __syncthreads();
      bool pref = (j < qt);
      if (pref) {
        const UST* kg = kbase + (size_t)(j + 1) * 8192;
        const UST* vg = vbase + (j + 1) * 128;
        pk0 = *(const uint4*)kg; pk1 = *(const uint4*)(kg + 8);
        pv0 = *(const uint4*)vg; pv1 = *(const uint4*)(vg + 8);
      }

      // S^T = K * Q^T : 16 MFMAs
      v4f st[8];
      __builtin_amdgcn_s_setprio(1);
#pragma unroll
      for (int kt = 0; kt < 8; ++kt) {
        const UST* kr = &k_s[(kt * 16 + lr) * 72 + lg * 8];
        v8bf kf0 = *(const v8bf*)kr;
        v8bf kf1 = *(const v8bf*)(kr + 32);
        v4f z = (v4f){0.f, 0.f, 0.f, 0.f};
        z = __builtin_amdgcn_mfma_f32_16x16x32_bf16(kf0, qf0, z, 0, 0, 0);
        z = __builtin_amdgcn_mfma_f32_16x16x32_bf16(kf1, qf1, z, 0, 0, 0);
        st[kt] = z;
      }
      __builtin_amdgcn_s_setprio(0);
      if (j == qt) {
        int qg = qbase + lr;
#pragma unroll
        for (int kt = 0; kt < 8; ++kt)
#pragma unroll
          for (int r = 0; r < 4; ++r) {
            int kg2 = j * 128 + kt * 16 + 4 * lg + r;
            if (kg2 > qg) st[kt][r] = -1e30f;
          }
      }

      float t0 = fmaxf(fmaxf(st[0][0], st[0][1]), fmaxf(st[0][2], st[0][3]));
      float t1 = fmaxf(fmaxf(st[1][0], st[1][1]), fmaxf(st[1][2], st[1][3]));
      float t2 = fmaxf(fmaxf(st[2][0], st[2][1]), fmaxf(st[2][2], st[2][3]));
      float t3 = fmaxf(fmaxf(st[3][0], st[3][1]), fmaxf(st[3][2], st[3][3]));
      float t4 = fmaxf(fmaxf(st[4][0], st[4][1]), fmaxf(st[4][2], st[4][3]));
      float t5 = fmaxf(fmaxf(st[5][0], st[5][1]), fmaxf(st[5][2], st[5][3]));
      float t6 = fmaxf(fmaxf(st[6][0], st[6][1]), fmaxf(st[6][2], st[6][3]));
      float t7 = fmaxf(fmaxf(st[7][0], st[7][1]), fmaxf(st[7][2], st[7][3]));
      float mx = fmaxf(fmaxf(fmaxf(t0, t1), fmaxf(t2, t3)),
                       fmaxf(fmaxf(t4, t5), fmaxf(t6, t7)));
      mx = fmaxf(mx, __shfl_xor(mx, 16));
      mx = fmaxf(mx, __shfl_xor(mx, 32));

      if (!__all(mx <= m + 8.f)) {   // defer-max (T13)
        float mn = fmaxf(m, mx);
        float al = __expf(m - mn);
        m = mn;
        ls *= al;
#pragma unroll
        for (int r = 0; r < 4; ++r) {
          float ar = __shfl(al, 4 * lg + r);
          o[0][r] *= ar; o[1][r] *= ar; o[2][r] *= ar; o[3][r] *= ar;
        }
      }

      constexpr float LOG2E = 1.44269504f;
      float mlog = m * LOG2E;
      float rs = 0.f;
      UST* pw = &p_s[w][lr * 136 + 4 * lg];
#pragma unroll
      for (int kt = 0; kt < 8; ++kt) {
        float p0 = fexp2(__builtin_fmaf(st[kt][0], LOG2E, -mlog));
        float p1 = fexp2(__builtin_fmaf(st[kt][1], LOG2E, -mlog));
        float p2 = fexp2(__builtin_fmaf(st[kt][2], LOG2E, -mlog));
        float p3 = fexp2(__builtin_fmaf(st[kt][3], LOG2E, -mlog));
        rs += (p0 + p1) + (p2 + p3);
        uint2 q2;
        q2.x = cvtpk(p0, p1);
        q2.y = cvtpk(p2, p3);
        *(uint2*)(pw + kt * 16) = q2;
      }
      rs += __shfl_xor(rs, 16);
      rs += __shfl_xor(rs, 32);
      ls += rs;

      // PV: 16 MFMAs
      __builtin_amdgcn_s_setprio(1);
#pragma unroll
      for (int kk = 0; kk < 4; ++kk) {
        v8bf pa = *(const v8bf*)&p_s[w][lr * 136 + kk * 32 + lg * 8];
#pragma unroll
        for (int dt = 0; dt < 4; ++dt) {
          v8bf vb = *(const v8bf*)&v_s[(dt * 16 + lr) * 136 + kk * 32 + lg * 8];
          o[dt] = __builtin_amdgcn_mfma_f32_16x16x32_bf16(pa, vb, o[dt], 0, 0, 0);
        }
      }
      __builtin_amdgcn_s_setprio(0);

      __syncthreads();
      if (pref) {
        *(uint4*)kdst = pk0; *(uint4*)(kdst + 8) = pk1;
        *(uint4*)vdst = pv0; *(uint4*)(vdst + 8) = pv1;
      }
    }

    float iv = 1.f / ls;
#pragma unroll
    for (int r = 0; r < 4; ++r) {
      float ivr = __shfl(iv, 4 * lg + r);
      size_t rowb = ((size_t)b * 2048 + qbase + 4 * lg + r) * 2048 + h * 64 + lr;
#pragma unroll
      for (int dt = 0; dt < 4; ++dt)
        outp[rowb + dt * 16] = f2b(o[dt][r] * ivr);
    }
  }
}

// ---------------- launch ----------------
extern "C" void kernel_launch(void* const* d_in, const int* in_sizes, int n_in,
                              void* d_out, int out_size, void* d_ws, size_t ws_size,
                              hipStream_t stream) {
  const float* x    = (const float*)d_in[0];
  const float* cosT = (const float*)d_in[2];
  const float* sinT = (const float*)d_in[3];
  const float* Wq   = (const float*)d_in[4];
  const float* Wk   = (const float*)d_in[5];
  const float* Wv   = (const float*)d_in[6];
  const float* Wo   = (const float*)d_in[7];
  const float* bo   = (const float*)d_in[8];
  float* out = (float*)d_out;

  char* ws = (char*)d_ws;
  UST* xb   = (UST*)(ws);                       // 16777216 B
  UST* wcat = (UST*)(ws + 16777216);            // 12582912 B
  UST* wot  = (UST*)(ws + 29360128);            //  8388608 B
  UST* qkv  = (UST*)(ws + 37748736);            // 25165824 B
  UST* qhp  = (UST*)(ws + 62914560);            // 16777216 B
  UST* khp  = (UST*)(ws + 79691776);            //  4194304 B
  UST* vtp  = (UST*)(ws + 83886080);            //  4194304 B
  UST* attn_o = xb;  // xb dead after QKV GEMM

  k_cast<<<4096, 256, 0, stream>>>(x, xb);
  k_castT<<<dim3(64, 64), dim3(32, 8), 0, stream>>>(Wq, wcat, 2048, 2048);
  k_castT<<<dim3(16, 64), dim3(32, 8), 0, stream>>>(Wk, wcat + (size_t)2048 * 2048, 512, 2048);
  k_castT<<<dim3(16, 64), dim3(32, 8), 0, stream>>>(Wv, wcat + (size_t)2560 * 2048, 512, 2048);
  k_castT<<<dim3(64, 64), dim3(32, 8), 0, stream>>>(Wo, wot, 2048, 2048);

  // QKV: M=4096, N=3072, K=2048; 256x256 tiles -> 12x16 = 192 blocks
  k_gemm2<256, 256, 2, 4, 0><<<192, 512, 0, stream>>>(xb, wcat, qkv, nullptr,
                                                      4096, 3072, 2048, 12);
  k_rope<<<20480, 256, 0, stream>>>(qkv, cosT, sinT, qhp, khp);
  k_vtrans<<<dim3(32, 16), 256, 0, stream>>>(qkv, vtp);
  k_attn<<<dim3(8, 32, 2), 512, 0, stream>>>(qhp, khp, vtp, attn_o);
  // out: M=4096, N=2048, K=2048; 256x128 tiles -> 16x16 = 256 blocks (full fill)
  k_gemm2<256, 128, 4, 2, 1><<<256, 512, 0, stream>>>(attn_o, wot, out, bo,
                                                      4096, 2048, 2048, 16);
}

// Round 5
// 206.113 us; speedup vs baseline: 1.9597x; 1.0656x over previous
//
#include <hip/hip_runtime.h>
#include <cstdint>

typedef unsigned short UST;
typedef __bf16 v8bf __attribute__((ext_vector_type(8)));
typedef float v4f __attribute__((ext_vector_type(4)));

static __device__ __forceinline__ UST f2b(float f) {
  union { float f; uint32_t u; } c; c.f = f;
  uint32_t u = c.u;
  u += 0x7fffu + ((u >> 16) & 1u);   // RNE
  return (UST)(u >> 16);
}
static __device__ __forceinline__ float b2f(UST h) {
  union { uint32_t u; float f; } c; c.u = ((uint32_t)h) << 16;
  return c.f;
}
static __device__ __forceinline__ uint32_t cvtpk(float lo, float hi) {
  uint32_t r;
  asm("v_cvt_pk_bf16_f32 %0, %1, %2" : "=v"(r) : "v"(lo), "v"(hi));
  return r;
}
static __device__ __forceinline__ float fexp2(float x) {  // 2^x
  float r;
  asm("v_exp_f32 %0, %1" : "=v"(r) : "v"(x));
  return r;
}
template <int N>
static __device__ __forceinline__ void wait_vm() {
  asm volatile("s_waitcnt vmcnt(%0)" :: "i"(N));
}

// async global->LDS, 16B per lane; global src per-lane, LDS dst wave-uniform+lane*16
static __device__ __forceinline__ void gl_lds16(const UST* g, UST* l) {
  __builtin_amdgcn_global_load_lds(
      (const __attribute__((address_space(1))) void*)g,
      (__attribute__((address_space(3))) void*)l, 16, 0, 0);
}

// ---------------- cast x f32 -> bf16, 8 elems/thread ----------------
__global__ __launch_bounds__(256) void k_cast(const float* __restrict__ src,
                                              UST* __restrict__ dst) {
  size_t i = (size_t)blockIdx.x * 256 + threadIdx.x;
  const float4* s4 = reinterpret_cast<const float4*>(src) + 2 * i;
  float4 a = s4[0], b = s4[1];
  union { UST s[8]; uint4 v; } r;
  r.s[0] = f2b(a.x); r.s[1] = f2b(a.y); r.s[2] = f2b(a.z); r.s[3] = f2b(a.w);
  r.s[4] = f2b(b.x); r.s[5] = f2b(b.y); r.s[6] = f2b(b.z); r.s[7] = f2b(b.w);
  reinterpret_cast<uint4*>(dst)[i] = r.v;
}

// ------------- transpose+cast: W [K][N] f32 -> dst [N][K] bf16 -------------
__global__ __launch_bounds__(256) void k_castT(const float* __restrict__ W,
                                               UST* __restrict__ dst, int N, int K) {
  __shared__ float tile[32][33];
  int nt = blockIdx.x * 32, kt = blockIdx.y * 32;
  int tx = threadIdx.x, ty = threadIdx.y;  // 32 x 8
#pragma unroll
  for (int r = 0; r < 4; ++r)
    tile[ty + r * 8][tx] = W[(size_t)(kt + ty + r * 8) * N + nt + tx];
  __syncthreads();
#pragma unroll
  for (int r = 0; r < 4; ++r)
    dst[(size_t)(nt + ty + r * 8) * K + kt + tx] = f2b(tile[tx][ty + r * 8]);
}

// ============ 8-phase counted-vmcnt GEMM: C[M][N] = A[M][K] * Bt[N][K]^T ============
// BM x BN tile, BK=64 (two 32-k s-halves), 512 thr = 8 waves (WM x WN).
// Template-faithful phase: {ds_read (pre-barrier) | stage issue | (vmcnt)}
//   -> barrier -> setprio1 MFMA setprio0 -> barrier.
// Stage order per K-tile: As0, Bs0(+vmcnt), As1, Bs1(+vmcnt); NKEEP = CA+CB calls
// (keeps exactly the two newest s-half groups in flight; never 0 mid-loop).
// BN=192: B s-half = 1 full 8KB call (all waves) + one 64-row call (waves 0-3);
// per-wave NKEEP differs (wave-uniform branch).
template <int BM, int BN, int WM, int WN, int NMH, int EPI>
__global__ __launch_bounds__(512, 2) void k_gemm2(const UST* __restrict__ A,
                                                  const UST* __restrict__ Bt,
                                                  void* __restrict__ Cv,
                                                  const float* __restrict__ bias,
                                                  int M, int N, int K, int ntn) {
  constexpr int WMR = BM / WM, WNR = BN / WN;
  constexpr int MF = WMR / 16, NF = WNR / 16, MH = MF / NMH;
  constexpr int CA = BM / 128;            // full 8KB A-calls per s-half
  constexpr int CBF = BN / 128;           // full B-calls per s-half
  constexpr int BREM = (BN % 128) / 64;   // extra 64-row call (waves 0-3)
  constexpr int AELEMS = 4 * BM * 32;     // 2buf x 2s x BM x 32
  __shared__ __align__(16) UST lds[AELEMS + 4 * BN * 32];

  int tid = threadIdx.x, w = tid >> 6, lane = tid & 63;
  int lr = lane & 15, lg = lane >> 4;
  int wm = w / WN, wn = w % WN;

  // bijective XCD swizzle (grid % 8 == 0)
  int q = (int)gridDim.x >> 3;
  int bid = (int)blockIdx.x;
  int swz = (bid & 7) * q + (bid >> 3);
  int mBlk = (swz / ntn) * BM, nBlk = (swz % ntn) * BN;

  v4f acc[MF][NF];
#pragma unroll
  for (int i = 0; i < MF; ++i)
#pragma unroll
    for (int j = 0; j < NF; ++j) acc[i][j] = (v4f){0.f, 0.f, 0.f, 0.f};

  // staging: thread t covers bytes t*16 of each 8KB chunk: row t/4, elems (t&3)*8
  int srow = tid >> 2, scol = (tid & 3) * 8;
  const UST* Abase = A + (size_t)(mBlk + srow) * K + scol;
  const UST* Bbase = Bt + (size_t)(nBlk + srow) * K + scol;
  int ldsW = w * 512;  // wave-uniform chunk base (elems)

  auto stageA = [&](int buf, int s, int kt) {
#pragma unroll
    for (int i = 0; i < CA; ++i)
      gl_lds16(Abase + (size_t)(i * 128) * K + kt * 64 + s * 32,
               &lds[(buf * 2 + s) * BM * 32 + i * 4096 + ldsW]);
  };
  auto stageB = [&](int buf, int s, int kt) {
#pragma unroll
    for (int i = 0; i < CBF; ++i)
      gl_lds16(Bbase + (size_t)(i * 128) * K + kt * 64 + s * 32,
               &lds[AELEMS + (buf * 2 + s) * BN * 32 + i * 4096 + ldsW]);
    if constexpr (BREM) {
      if (w < 4)  // rows CBF*128 .. CBF*128+63 (256 lanes x 16B)
        gl_lds16(Bbase + (size_t)(CBF * 128) * K + kt * 64 + s * 32,
                 &lds[AELEMS + (buf * 2 + s) * BN * 32 + CBF * 4096 + ldsW]);
    }
  };
  auto waitNK = [&]() {
    if constexpr (BREM) {
      if (w < 4) wait_vm<CA + CBF + 1>();
      else       wait_vm<CA + CBF>();
    } else {
      wait_vm<CA + CBF>();
    }
  };
  auto ldA = [&](int buf, int s, int f) -> v8bf {
    int row = wm * WMR + f * 16 + lr;
    return *(const v8bf*)&lds[((buf * 2 + s) * BM + row) * 32 + lg * 8];
  };
  auto ldB = [&](int buf, int s, int nf) -> v8bf {
    int row = wn * WNR + nf * 16 + lr;
    return *(const v8bf*)&lds[AELEMS + ((buf * 2 + s) * BN + row) * 32 + lg * 8];
  };

  int NT = K >> 6;  // K-tiles of 64
  // prologue: stage tile 0 fully; keep newest s1 group in flight
  stageA(0, 0, 0); stageB(0, 0, 0); stageA(0, 1, 0); stageB(0, 1, 0);
  waitNK();
  __builtin_amdgcn_s_barrier();

  for (int kt = 0; kt < NT; ++kt) {
    int buf = kt & 1, nb = buf ^ 1;
    bool more = (kt + 1 < NT);
#pragma unroll
    for (int s = 0; s < 2; ++s) {
      v8bf bfr[NF];
#pragma unroll
      for (int mh = 0; mh < NMH; ++mh) {
        // ---- pre-barrier slot: ds_read current subtile + stage next ----
        v8bf afr[MH];
        if (mh == 0) {
#pragma unroll
          for (int nf = 0; nf < NF; ++nf) bfr[nf] = ldB(buf, s, nf);
        }
#pragma unroll
        for (int f = 0; f < MH; ++f) afr[f] = ldA(buf, s, mh * MH + f);
        if constexpr (NMH == 2) {
          if (mh == 0) {
            if (more) stageA(nb, s, kt + 1);
          } else {
            if (more) { stageB(nb, s, kt + 1); waitNK(); }
            else if (s == 0) wait_vm<0>();
          }
        } else {
          if (more) { stageA(nb, s, kt + 1); stageB(nb, s, kt + 1); waitNK(); }
          else if (s == 0) wait_vm<0>();
        }
        __builtin_amdgcn_s_barrier();
        __builtin_amdgcn_s_setprio(1);
#pragma unroll
        for (int f = 0; f < MH; ++f)
#pragma unroll
          for (int nf = 0; nf < NF; ++nf)
            acc[mh * MH + f][nf] = __builtin_amdgcn_mfma_f32_16x16x32_bf16(
                afr[f], bfr[nf], acc[mh * MH + f][nf], 0, 0, 0);
        __builtin_amdgcn_s_setprio(0);
        __builtin_amdgcn_s_barrier();
      }
    }
  }

  // epilogue: C/D layout col = lane&15, row = 4*(lane>>4)+reg
  int row0 = mBlk + wm * WMR + lg * 4;
  int col0 = nBlk + wn * WNR + lr;
#pragma unroll
  for (int fm = 0; fm < MF; ++fm)
#pragma unroll
    for (int nf = 0; nf < NF; ++nf)
#pragma unroll
      for (int r = 0; r < 4; ++r) {
        int row = row0 + fm * 16 + r;
        int col = col0 + nf * 16;
        if constexpr (EPI == 0) {
          ((UST*)Cv)[(size_t)row * N + col] = f2b(acc[fm][nf][r]);
        } else {
          ((float*)Cv)[(size_t)row * N + col] = acc[fm][nf][r] + bias[col];
        }
      }
}

// ---------------- RoPE on q,k (q pre-scaled by 1/sqrt(64)) ----------------
__global__ __launch_bounds__(256) void k_rope(const UST* __restrict__ qkv,
                                              const float* __restrict__ cosT,
                                              const float* __restrict__ sinT,
                                              UST* __restrict__ qh,
                                              UST* __restrict__ kh) {
  int idx = blockIdx.x * 256 + threadIdx.x;
  int d = idx & 31;
  int hh = (idx >> 5) % 40;
  int row = idx / 1280;
  int l = row & 2047, b = row >> 11;
  int col = (hh < 32) ? hh * 64 : 2048 + (hh - 32) * 64;
  float t1 = b2f(qkv[(size_t)row * 3072 + col + d]);
  float t2 = b2f(qkv[(size_t)row * 3072 + col + d + 32]);
  float c = cosT[l * 64 + d], s = sinT[l * 64 + d];
  float o1 = t1 * c - t2 * s;
  float o2 = t2 * c + t1 * s;
  if (hh < 32) {
    size_t base = (((size_t)b * 32 + hh) * 2048 + l) * 64 + d;
    qh[base] = f2b(o1 * 0.125f);
    qh[base + 32] = f2b(o2 * 0.125f);
  } else {
    size_t base = (((size_t)b * 8 + (hh - 32)) * 2048 + l) * 64 + d;
    kh[base] = f2b(o1);
    kh[base + 32] = f2b(o2);
  }
}

// ---------------- V transpose: qkv v-slice -> vt [B][8][64][L] ----------------
__global__ __launch_bounds__(256) void k_vtrans(const UST* __restrict__ qkv,
                                                UST* __restrict__ vt) {
  __shared__ __align__(16) UST tl[64][72];
  int lt = blockIdx.x, bg = blockIdx.y;
  int b = bg >> 3, g = bg & 7;
  int t = threadIdx.x;
  int li = t >> 2, d0 = (t & 3) * 16;
  const UST* src = qkv + (size_t)(b * 2048 + lt * 64 + li) * 3072 + 2560 + g * 64 + d0;
  *(uint4*)&tl[li][d0] = *(const uint4*)src;
  *(uint4*)&tl[li][d0 + 8] = *(const uint4*)(src + 8);
  __syncthreads();
  int d = t >> 2, l0 = (t & 3) * 16;
  union { UST u[8]; uint4 v; } r0, r1;
#pragma unroll
  for (int e = 0; e < 8; ++e) r0.u[e] = tl[l0 + e][d];
#pragma unroll
  for (int e = 0; e < 8; ++e) r1.u[e] = tl[l0 + 8 + e][d];
  UST* dstp = vt + (size_t)((b * 8 + g) * 64 + d) * 2048 + (size_t)lt * 64 + l0;
  *(uint4*)dstp = r0.v;
  *(uint4*)(dstp + 8) = r1.v;
}

// ---------------- causal flash attention: balanced pairs, KVBLK=128 ----------------
__global__ __launch_bounds__(512, 4) void k_attn(const UST* __restrict__ qh,
                                                 const UST* __restrict__ kh,
                                                 const UST* __restrict__ vt,
                                                 UST* __restrict__ outp) {
  __shared__ __align__(16) UST k_s[128 * 72];
  __shared__ __align__(16) UST v_s[64 * 136];
  __shared__ __align__(16) UST p_s[8][16 * 136];
  int bx = blockIdx.x, h = blockIdx.y, b = blockIdx.z;
  int g = h >> 2;
  int tid = threadIdx.x, w = tid >> 6, lane = tid & 63;
  int lr = lane & 15, lg = lane >> 4;

  int ksr = tid >> 2, ksc = (tid & 3) * 16;
  int vsr = tid >> 3, vsc = (tid & 7) * 16;
  const UST* kbase = kh + ((size_t)(b * 8 + g) * 2048 + ksr) * 64 + ksc;
  const UST* vbase = vt + ((size_t)(b * 8 + g) * 64 + vsr) * 2048 + vsc;
  UST* kdst = &k_s[ksr * 72 + ksc];
  UST* vdst = &v_s[vsr * 136 + vsc];

  for (int half = 0; half < 2; ++half) {
    int qt = half ? (15 - bx) : bx;
    int qbase = qt * 128 + w * 16;

    const UST* qp = qh + ((size_t)(b * 32 + h) * 2048 + qbase + lr) * 64 + lg * 8;
    v8bf qf0 = *(const v8bf*)qp;
    v8bf qf1 = *(const v8bf*)(qp + 32);

    float m = -1e30f, ls = 0.f;
    v4f o[4];
#pragma unroll
    for (int dt = 0; dt < 4; ++dt) o[dt] = (v4f){0.f, 0.f, 0.f, 0.f};

    __syncthreads();
    uint4 pk0 = *(const uint4*)kbase, pk1 = *(const uint4*)(kbase + 8);
    uint4 pv0 = *(const uint4*)vbase, pv1 = *(const uint4*)(vbase + 8);
    *(uint4*)kdst = pk0; *(uint4*)(kdst + 8) = pk1;
    *(uint4*)vdst = pv0; *(uint4*)(vdst + 8) = pv1;

    for (int j = 0; j <= qt; ++j) {
      __syncthreads();
      bool pref = (j < qt);
      if (pref) {
        const UST* kg = kbase + (size_t)(j + 1) * 8192;
        const UST* vg = vbase + (j + 1) * 128;
        pk0 = *(const uint4*)kg; pk1 = *(const uint4*)(kg + 8);
        pv0 = *(const uint4*)vg; pv1 = *(const uint4*)(vg + 8);
      }

      // S^T = K * Q^T : 16 MFMAs
      v4f st[8];
      __builtin_amdgcn_s_setprio(1);
#pragma unroll
      for (int kt = 0; kt < 8; ++kt) {
        const UST* kr = &k_s[(kt * 16 + lr) * 72 + lg * 8];
        v8bf kf0 = *(const v8bf*)kr;
        v8bf kf1 = *(const v8bf*)(kr + 32);
        v4f z = (v4f){0.f, 0.f, 0.f, 0.f};
        z = __builtin_amdgcn_mfma_f32_16x16x32_bf16(kf0, qf0, z, 0, 0, 0);
        z = __builtin_amdgcn_mfma_f32_16x16x32_bf16(kf1, qf1, z, 0, 0, 0);
        st[kt] = z;
      }
      __builtin_amdgcn_s_setprio(0);
      if (j == qt) {
        int qg = qbase + lr;
#pragma unroll
        for (int kt = 0; kt < 8; ++kt)
#pragma unroll
          for (int r = 0; r < 4; ++r) {
            int kg2 = j * 128 + kt * 16 + 4 * lg + r;
            if (kg2 > qg) st[kt][r] = -1e30f;
          }
      }

      float t0 = fmaxf(fmaxf(st[0][0], st[0][1]), fmaxf(st[0][2], st[0][3]));
      float t1 = fmaxf(fmaxf(st[1][0], st[1][1]), fmaxf(st[1][2], st[1][3]));
      float t2 = fmaxf(fmaxf(st[2][0], st[2][1]), fmaxf(st[2][2], st[2][3]));
      float t3 = fmaxf(fmaxf(st[3][0], st[3][1]), fmaxf(st[3][2], st[3][3]));
      float t4 = fmaxf(fmaxf(st[4][0], st[4][1]), fmaxf(st[4][2], st[4][3]));
      float t5 = fmaxf(fmaxf(st[5][0], st[5][1]), fmaxf(st[5][2], st[5][3]));
      float t6 = fmaxf(fmaxf(st[6][0], st[6][1]), fmaxf(st[6][2], st[6][3]));
      float t7 = fmaxf(fmaxf(st[7][0], st[7][1]), fmaxf(st[7][2], st[7][3]));
      float mx = fmaxf(fmaxf(fmaxf(t0, t1), fmaxf(t2, t3)),
                       fmaxf(fmaxf(t4, t5), fmaxf(t6, t7)));
      mx = fmaxf(mx, __shfl_xor(mx, 16));
      mx = fmaxf(mx, __shfl_xor(mx, 32));

      if (!__all(mx <= m + 8.f)) {   // defer-max (T13)
        float mn = fmaxf(m, mx);
        float al = __expf(m - mn);
        m = mn;
        ls *= al;
#pragma unroll
        for (int r = 0; r < 4; ++r) {
          float ar = __shfl(al, 4 * lg + r);
          o[0][r] *= ar; o[1][r] *= ar; o[2][r] *= ar; o[3][r] *= ar;
        }
      }

      constexpr float LOG2E = 1.44269504f;
      float mlog = m * LOG2E;
      float rs = 0.f;
      UST* pw = &p_s[w][lr * 136 + 4 * lg];
#pragma unroll
      for (int kt = 0; kt < 8; ++kt) {
        float p0 = fexp2(__builtin_fmaf(st[kt][0], LOG2E, -mlog));
        float p1 = fexp2(__builtin_fmaf(st[kt][1], LOG2E, -mlog));
        float p2 = fexp2(__builtin_fmaf(st[kt][2], LOG2E, -mlog));
        float p3 = fexp2(__builtin_fmaf(st[kt][3], LOG2E, -mlog));
        rs += (p0 + p1) + (p2 + p3);
        uint2 q2;
        q2.x = cvtpk(p0, p1);
        q2.y = cvtpk(p2, p3);
        *(uint2*)(pw + kt * 16) = q2;
      }
      rs += __shfl_xor(rs, 16);
      rs += __shfl_xor(rs, 32);
      ls += rs;

      // PV: 16 MFMAs
      __builtin_amdgcn_s_setprio(1);
#pragma unroll
      for (int kk = 0; kk < 4; ++kk) {
        v8bf pa = *(const v8bf*)&p_s[w][lr * 136 + kk * 32 + lg * 8];
#pragma unroll
        for (int dt = 0; dt < 4; ++dt) {
          v8bf vb = *(const v8bf*)&v_s[(dt * 16 + lr) * 136 + kk * 32 + lg * 8];
          o[dt] = __builtin_amdgcn_mfma_f32_16x16x32_bf16(pa, vb, o[dt], 0, 0, 0);
        }
      }
      __builtin_amdgcn_s_setprio(0);

      __syncthreads();
      if (pref) {
        *(uint4*)kdst = pk0; *(uint4*)(kdst + 8) = pk1;
        *(uint4*)vdst = pv0; *(uint4*)(vdst + 8) = pv1;
      }
    }

    float iv = 1.f / ls;
#pragma unroll
    for (int r = 0; r < 4; ++r) {
      float ivr = __shfl(iv, 4 * lg + r);
      size_t rowb = ((size_t)b * 2048 + qbase + 4 * lg + r) * 2048 + h * 64 + lr;
#pragma unroll
      for (int dt = 0; dt < 4; ++dt)
        outp[rowb + dt * 16] = f2b(o[dt][r] * ivr);
    }
  }
}

// ---------------- launch ----------------
extern "C" void kernel_launch(void* const* d_in, const int* in_sizes, int n_in,
                              void* d_out, int out_size, void* d_ws, size_t ws_size,
                              hipStream_t stream) {
  const float* x    = (const float*)d_in[0];
  const float* cosT = (const float*)d_in[2];
  const float* sinT = (const float*)d_in[3];
  const float* Wq   = (const float*)d_in[4];
  const float* Wk   = (const float*)d_in[5];
  const float* Wv   = (const float*)d_in[6];
  const float* Wo   = (const float*)d_in[7];
  const float* bo   = (const float*)d_in[8];
  float* out = (float*)d_out;

  char* ws = (char*)d_ws;
  UST* xb   = (UST*)(ws);                       // 16777216 B
  UST* wcat = (UST*)(ws + 16777216);            // 12582912 B
  UST* wot  = (UST*)(ws + 29360128);            //  8388608 B
  UST* qkv  = (UST*)(ws + 37748736);            // 25165824 B
  UST* qhp  = (UST*)(ws + 62914560);            // 16777216 B
  UST* khp  = (UST*)(ws + 79691776);            //  4194304 B
  UST* vtp  = (UST*)(ws + 83886080);            //  4194304 B
  UST* attn_o = xb;  // xb dead after QKV GEMM

  k_cast<<<4096, 256, 0, stream>>>(x, xb);
  k_castT<<<dim3(64, 64), dim3(32, 8), 0, stream>>>(Wq, wcat, 2048, 2048);
  k_castT<<<dim3(16, 64), dim3(32, 8), 0, stream>>>(Wk, wcat + (size_t)2048 * 2048, 512, 2048);
  k_castT<<<dim3(16, 64), dim3(32, 8), 0, stream>>>(Wv, wcat + (size_t)2560 * 2048, 512, 2048);
  k_castT<<<dim3(64, 64), dim3(32, 8), 0, stream>>>(Wo, wot, 2048, 2048);

  // QKV: M=4096, N=3072, K=2048; 256x192 tiles -> 16x16 = 256 blocks (perfect fill)
  k_gemm2<256, 192, 2, 4, 2, 0><<<256, 512, 0, stream>>>(xb, wcat, qkv, nullptr,
                                                         4096, 3072, 2048, 16);
  k_rope<<<20480, 256, 0, stream>>>(qkv, cosT, sinT, qhp, khp);
  k_vtrans<<<dim3(32, 16), 256, 0, stream>>>(qkv, vtp);
  k_attn<<<dim3(8, 32, 2), 512, 0, stream>>>(qhp, khp, vtp, attn_o);
  // out: M=4096, N=2048, K=2048; 256x128 tiles -> 16x16 = 256 blocks (full fill)
  k_gemm2<256, 128, 4, 2, 1, 1><<<256, 512, 0, stream>>>(attn_o, wot, out, bo,
                                                         4096, 2048, 2048, 16);
}